// Round 1
// baseline (2990.384 us; speedup 1.0000x reference)
//
#include <hip/hip_runtime.h>
#include <hip/hip_bf16.h>
#include <math.h>

// Problem constants (fixed by reference)
#define NH 32
#define NKV 8
#define HD 64
constexpr int SEQ  = 2048;
constexpr int DIM  = 2048;
constexpr int MROWS = 2 * SEQ;   // B*S = 4096

// ---------------------------------------------------------------------------
// RoPE cos/sin tables: [S][32]. inv_freq computed in double then rounded to
// f32 to match jnp's fp32 inv_freq closely; cosf/sinf of fp32 angle.
// ---------------------------------------------------------------------------
__global__ __launch_bounds__(256) void rope_table_k(float* __restrict__ cosT,
                                                    float* __restrict__ sinT) {
    int i = blockIdx.x * 256 + threadIdx.x;   // i < SEQ*32
    int s = i >> 5, p = i & 31;
    float inv = (float)pow(10000.0, -(double)p / 32.0);
    float a = (float)s * inv;
    cosT[i] = cosf(a);
    sinT[i] = sinf(a);
}

// ---------------------------------------------------------------------------
// fp32 tiled GEMM: C = A[M,K] @ B[K,N].  BM=BN=128, BK=8, 256 thr, 8x8 micro.
// MODE 0: plain row-major C[M][N]
// MODE 1: headed store  C[((b*HEADS+h)*SEQ+s)*64+d]
// MODE 2: headed store + RoPE epilogue
// ---------------------------------------------------------------------------
template<int MODE, int HEADS>
__global__ __launch_bounds__(256) void gemm128(const float* __restrict__ A,
                                               const float* __restrict__ Bw,
                                               float* __restrict__ C,
                                               int M, int N, int K,
                                               const float* __restrict__ cosT,
                                               const float* __restrict__ sinT) {
    __shared__ float As[8][132];   // transposed A tile [k][m], pad->132 (16B-aligned rows)
    __shared__ float Bs[8][132];

    const int t  = threadIdx.x;
    const int m0 = blockIdx.y * 128;
    const int n0 = blockIdx.x * 128;
    const int ty = t >> 4, tx = t & 15;

    float acc[8][8];
#pragma unroll
    for (int i = 0; i < 8; i++)
#pragma unroll
        for (int j = 0; j < 8; j++) acc[i][j] = 0.f;

    const int ar  = t >> 1;          // 0..127 A-tile row
    const int akc = (t & 1) * 4;     // k sub-col
    const int br  = t >> 5;          // 0..7  B-tile k-row
    const int bc  = (t & 31) * 4;    // B col
    const float* Aptr = A + (long)(m0 + ar) * K + akc;
    const float* Bptr = Bw + (long)br * N + n0 + bc;

    for (int k0 = 0; k0 < K; k0 += 8) {
        __syncthreads();
        float4 av = *(const float4*)(Aptr + k0);
        float4 bv = *(const float4*)(Bptr + (long)k0 * N);
        As[akc + 0][ar] = av.x;
        As[akc + 1][ar] = av.y;
        As[akc + 2][ar] = av.z;
        As[akc + 3][ar] = av.w;
        *(float4*)&Bs[br][bc] = bv;
        __syncthreads();
#pragma unroll
        for (int kk = 0; kk < 8; kk++) {
            float a[8], b[8];
            *(float4*)&a[0] = *(const float4*)&As[kk][ty * 8];
            *(float4*)&a[4] = *(const float4*)&As[kk][ty * 8 + 4];
            *(float4*)&b[0] = *(const float4*)&Bs[kk][tx * 8];
            *(float4*)&b[4] = *(const float4*)&Bs[kk][tx * 8 + 4];
#pragma unroll
            for (int i = 0; i < 8; i++)
#pragma unroll
                for (int j = 0; j < 8; j++)
                    acc[i][j] = fmaf(a[i], b[j], acc[i][j]);
        }
    }

#pragma unroll
    for (int i = 0; i < 8; i++) {
        int m = m0 + ty * 8 + i;
        int cb = n0 + tx * 8;
        if constexpr (MODE == 0) {
            float4 v0 = {acc[i][0], acc[i][1], acc[i][2], acc[i][3]};
            float4 v1 = {acc[i][4], acc[i][5], acc[i][6], acc[i][7]};
            *(float4*)(C + (long)m * N + cb)     = v0;
            *(float4*)(C + (long)m * N + cb + 4) = v1;
        } else {
            int b = m >> 11, s = m & (SEQ - 1);
            int h = cb >> 6, d = cb & 63;          // 8 cols all within one head
            float vo[8];
            if constexpr (MODE == 2) {
#pragma unroll
                for (int jp = 0; jp < 4; jp++) {
                    int p = (d >> 1) + jp;
                    float cc = cosT[s * 32 + p];
                    float ss = sinT[s * 32 + p];
                    float x0 = acc[i][2 * jp], x1 = acc[i][2 * jp + 1];
                    vo[2 * jp]     = x0 * cc - x1 * ss;
                    vo[2 * jp + 1] = x0 * ss + x1 * cc;
                }
            } else {
#pragma unroll
                for (int j = 0; j < 8; j++) vo[j] = acc[i][j];
            }
            float* dst = C + (((long)b * HEADS + h) * SEQ + s) * 64 + d;
            *(float4*)dst       = *(float4*)&vo[0];
            *(float4*)(dst + 4) = *(float4*)&vo[4];
        }
    }
}

// ---------------------------------------------------------------------------
// fp32 flash attention. Grid (S/32, B*NH), 256 thr.
// Thread (r = t>>3, g = t&7): q-row r, score cols g*4..+3, out dims g*8..+7.
// Q layout [B][NH][S][64]; K/V [B][NKV][S][64]; out [B*S][2048].
// ---------------------------------------------------------------------------
__global__ __launch_bounds__(256) void attn_k(const float* __restrict__ Q,
                                              const float* __restrict__ Kb,
                                              const float* __restrict__ Vb,
                                              float* __restrict__ O) {
    __shared__ float Ks[32][68];
    __shared__ float Vs[32][68];
    __shared__ float Ps[32][36];

    const int t = threadIdx.x;
    const int r = t >> 3, g = t & 7;
    const int qt = blockIdx.x, bh = blockIdx.y;
    const int b = bh >> 5, h = bh & 31;
    const int hk = h >> 2;
    const int q0 = qt * 32;

    const float* qp = Q + (((long)b * NH + h) * SEQ + q0) * 64;
    const float* kp = Kb + (((long)b * NKV + hk) * SEQ) * 64;
    const float* vp = Vb + (((long)b * NKV + hk) * SEQ) * 64;

    // stage Q tile through LDS (coalesced), read row to regs, scale by 1/8
    {
        int rr = t >> 3, cc = (t & 7) * 8;
        *(float4*)&Ks[rr][cc]     = *(const float4*)(qp + rr * 64 + cc);
        *(float4*)&Ks[rr][cc + 4] = *(const float4*)(qp + rr * 64 + cc + 4);
    }
    __syncthreads();
    float4 q[16];
#pragma unroll
    for (int d4 = 0; d4 < 16; d4++) {
        q[d4] = *(const float4*)&Ks[r][d4 * 4];
        q[d4].x *= 0.125f; q[d4].y *= 0.125f; q[d4].z *= 0.125f; q[d4].w *= 0.125f;
    }

    float m = -1e30f, l = 0.f;
    float o[8];
#pragma unroll
    for (int j = 0; j < 8; j++) o[j] = 0.f;

    const int nt = qt + 1;
    for (int kt = 0; kt < nt; kt++) {
        const int k0 = kt * 32;
        __syncthreads();   // prev PV done before overwrite
        {
            int rr = t >> 3, cc = (t & 7) * 8;
            const float* ksrc = kp + (long)(k0 + rr) * 64 + cc;
            const float* vsrc = vp + (long)(k0 + rr) * 64 + cc;
            *(float4*)&Ks[rr][cc]     = *(const float4*)(ksrc);
            *(float4*)&Ks[rr][cc + 4] = *(const float4*)(ksrc + 4);
            *(float4*)&Vs[rr][cc]     = *(const float4*)(vsrc);
            *(float4*)&Vs[rr][cc + 4] = *(const float4*)(vsrc + 4);
        }
        __syncthreads();

        float sc[4];
#pragma unroll
        for (int c = 0; c < 4; c++) {
            int kr = g * 4 + c;
            float acc = 0.f;
#pragma unroll
            for (int d4 = 0; d4 < 16; d4++) {
                float4 kv = *(const float4*)&Ks[kr][d4 * 4];
                acc = fmaf(q[d4].x, kv.x, acc);
                acc = fmaf(q[d4].y, kv.y, acc);
                acc = fmaf(q[d4].z, kv.z, acc);
                acc = fmaf(q[d4].w, kv.w, acc);
            }
            int kpos = k0 + kr, qpos = q0 + r;
            sc[c] = (kpos <= qpos) ? acc : -1e30f;
        }

        float mx = fmaxf(fmaxf(sc[0], sc[1]), fmaxf(sc[2], sc[3]));
        mx = fmaxf(mx, __shfl_xor(mx, 1));
        mx = fmaxf(mx, __shfl_xor(mx, 2));
        mx = fmaxf(mx, __shfl_xor(mx, 4));
        float mnew  = fmaxf(m, mx);
        float alpha = __expf(m - mnew);
        float p[4], ps = 0.f;
#pragma unroll
        for (int c = 0; c < 4; c++) { p[c] = __expf(sc[c] - mnew); ps += p[c]; }
        ps += __shfl_xor(ps, 1);
        ps += __shfl_xor(ps, 2);
        ps += __shfl_xor(ps, 4);
        l = l * alpha + ps;
        m = mnew;
#pragma unroll
        for (int j = 0; j < 8; j++) o[j] *= alpha;
        Ps[r][g * 4 + 0] = p[0];
        Ps[r][g * 4 + 1] = p[1];
        Ps[r][g * 4 + 2] = p[2];
        Ps[r][g * 4 + 3] = p[3];
        __syncthreads();

#pragma unroll
        for (int k = 0; k < 32; k++) {
            float pk = Ps[r][k];
            float4 v0 = *(const float4*)&Vs[k][g * 8];
            float4 v1 = *(const float4*)&Vs[k][g * 8 + 4];
            o[0] = fmaf(pk, v0.x, o[0]);
            o[1] = fmaf(pk, v0.y, o[1]);
            o[2] = fmaf(pk, v0.z, o[2]);
            o[3] = fmaf(pk, v0.w, o[3]);
            o[4] = fmaf(pk, v1.x, o[4]);
            o[5] = fmaf(pk, v1.y, o[5]);
            o[6] = fmaf(pk, v1.z, o[6]);
            o[7] = fmaf(pk, v1.w, o[7]);
        }
    }

    float inv = 1.f / l;
    float4 o0 = {o[0] * inv, o[1] * inv, o[2] * inv, o[3] * inv};
    float4 o1 = {o[4] * inv, o[5] * inv, o[6] * inv, o[7] * inv};
    float* dst = O + ((long)(b * SEQ + q0 + r)) * (NH * HD) + h * 64 + g * 8;
    *(float4*)dst       = o0;
    *(float4*)(dst + 4) = o1;
}

// ---------------------------------------------------------------------------
extern "C" void kernel_launch(void* const* d_in, const int* in_sizes, int n_in,
                              void* d_out, int out_size, void* d_ws, size_t ws_size,
                              hipStream_t stream) {
    const float* x  = (const float*)d_in[0];
    const float* wq = (const float*)d_in[1];
    const float* wk = (const float*)d_in[2];
    const float* wv = (const float*)d_in[3];
    const float* wo = (const float*)d_in[4];
    float* out = (float*)d_out;

    char* ws = (char*)d_ws;
    float* cosT = (float*)ws;                         // 256 KB
    float* sinT = (float*)(ws + 262144);              // 256 KB
    float* qb   = (float*)(ws + 524288);              // 32 MB  [B][32][S][64]
    float* kb   = qb + (long)2 * NH * SEQ * HD;       // 8 MB   [B][8][S][64]
    float* vb   = kb + (long)2 * NKV * SEQ * HD;      // 8 MB
    float* ao   = vb + (long)2 * NKV * SEQ * HD;      // 32 MB  [B*S][2048]

    rope_table_k<<<SEQ * 32 / 256, 256, 0, stream>>>(cosT, sinT);

    // QKV projections (+RoPE on Q,K), headed layouts
    gemm128<2, NH> <<<dim3(2048 / 128, MROWS / 128), 256, 0, stream>>>(
        x, wq, qb, MROWS, 2048, DIM, cosT, sinT);
    gemm128<2, NKV><<<dim3(512 / 128, MROWS / 128), 256, 0, stream>>>(
        x, wk, kb, MROWS, 512, DIM, cosT, sinT);
    gemm128<1, NKV><<<dim3(512 / 128, MROWS / 128), 256, 0, stream>>>(
        x, wv, vb, MROWS, 512, DIM, nullptr, nullptr);

    // causal GQA flash attention
    attn_k<<<dim3(SEQ / 32, 2 * NH), 256, 0, stream>>>(qb, kb, vb, ao);

    // output projection
    gemm128<0, 1><<<dim3(2048 / 128, MROWS / 128), 256, 0, stream>>>(
        ao, wo, out, MROWS, 2048, DIM, nullptr, nullptr);
}

// Round 3
// 1861.198 us; speedup vs baseline: 1.6067x; 1.6067x over previous
//
#include <hip/hip_runtime.h>
#include <hip/hip_bf16.h>
#include <math.h>

// Problem constants (fixed by reference)
#define NH 32
#define NKV 8
#define HD 64
constexpr int SEQ  = 2048;
constexpr int DIM  = 2048;
constexpr int MROWS = 2 * SEQ;   // B*S = 4096

typedef __attribute__((ext_vector_type(8))) short bf16x8;   // 8 bf16 = 4 VGPRs (MFMA A/B frag)
typedef __attribute__((ext_vector_type(4))) float f32x4;    // MFMA C/D frag

__device__ __forceinline__ unsigned short f2bf(float f) {   // RNE float->bf16
    unsigned int u = __float_as_uint(f);
    u += 0x7fffu + ((u >> 16) & 1u);
    return (unsigned short)(u >> 16);
}

// ---------------------------------------------------------------------------
// RoPE cos/sin tables: [S][32].
// ---------------------------------------------------------------------------
__global__ __launch_bounds__(256) void rope_table_k(float* __restrict__ cosT,
                                                    float* __restrict__ sinT) {
    int i = blockIdx.x * 256 + threadIdx.x;   // i < SEQ*32
    int s = i >> 5, p = i & 31;
    float inv = (float)pow(10000.0, -(double)p / 32.0);
    float a = (float)s * inv;
    cosT[i] = cosf(a);
    sinT[i] = sinf(a);
}

// ---------------------------------------------------------------------------
// fp32 tiled GEMM: C = A[M,K] @ B[K,N].  BM=BN=128, BK=8, 256 thr, 8x8 micro.
// MODE 0: fp32 row-major C[M][N]
// MODE 2: bf16 headed store + RoPE epilogue (HEADS==NH -> extra *0.125 scale)
// MODE 3: bf16 TRANSPOSED store  C[((b*HEADS+h)*64+d)*SEQ + s]   (for V)
// ---------------------------------------------------------------------------
template<int MODE, int HEADS>
__global__ __launch_bounds__(256) void gemm128(const float* __restrict__ A,
                                               const float* __restrict__ Bw,
                                               void* __restrict__ Cv,
                                               int M, int N, int K,
                                               const float* __restrict__ cosT,
                                               const float* __restrict__ sinT) {
    __shared__ float As[8][132];   // transposed A tile [k][m]
    __shared__ float Bs[8][132];

    const int t  = threadIdx.x;
    const int m0 = blockIdx.y * 128;
    const int n0 = blockIdx.x * 128;
    const int ty = t >> 4, tx = t & 15;

    float acc[8][8];
#pragma unroll
    for (int i = 0; i < 8; i++)
#pragma unroll
        for (int j = 0; j < 8; j++) acc[i][j] = 0.f;

    const int ar  = t >> 1;
    const int akc = (t & 1) * 4;
    const int br  = t >> 5;
    const int bc  = (t & 31) * 4;
    const float* Aptr = A + (long)(m0 + ar) * K + akc;
    const float* Bptr = Bw + (long)br * N + n0 + bc;

    for (int k0 = 0; k0 < K; k0 += 8) {
        __syncthreads();
        float4 av = *(const float4*)(Aptr + k0);
        float4 bv = *(const float4*)(Bptr + (long)k0 * N);
        As[akc + 0][ar] = av.x;
        As[akc + 1][ar] = av.y;
        As[akc + 2][ar] = av.z;
        As[akc + 3][ar] = av.w;
        *(float4*)&Bs[br][bc] = bv;
        __syncthreads();
#pragma unroll
        for (int kk = 0; kk < 8; kk++) {
            float a[8], b[8];
            *(float4*)&a[0] = *(const float4*)&As[kk][ty * 8];
            *(float4*)&a[4] = *(const float4*)&As[kk][ty * 8 + 4];
            *(float4*)&b[0] = *(const float4*)&Bs[kk][tx * 8];
            *(float4*)&b[4] = *(const float4*)&Bs[kk][tx * 8 + 4];
#pragma unroll
            for (int i = 0; i < 8; i++)
#pragma unroll
                for (int j = 0; j < 8; j++)
                    acc[i][j] = fmaf(a[i], b[j], acc[i][j]);
        }
    }

    const int cb = n0 + tx * 8;
    if constexpr (MODE == 0) {
        float* C = (float*)Cv;
#pragma unroll
        for (int i = 0; i < 8; i++) {
            int m = m0 + ty * 8 + i;
            float4 v0 = {acc[i][0], acc[i][1], acc[i][2], acc[i][3]};
            float4 v1 = {acc[i][4], acc[i][5], acc[i][6], acc[i][7]};
            *(float4*)(C + (long)m * N + cb)     = v0;
            *(float4*)(C + (long)m * N + cb + 4) = v1;
        }
    } else if constexpr (MODE == 2) {
        unsigned short* C = (unsigned short*)Cv;
        constexpr float qsc = (HEADS == NH) ? 0.125f : 1.0f;   // fold softmax 1/sqrt(64) into Q
        const int h = cb >> 6, d = cb & 63;
#pragma unroll
        for (int i = 0; i < 8; i++) {
            int m = m0 + ty * 8 + i;
            int b = m >> 11, s = m & (SEQ - 1);
            unsigned short o8[8];
#pragma unroll
            for (int jp = 0; jp < 4; jp++) {
                int p = (d >> 1) + jp;
                float cc = cosT[s * 32 + p];
                float ss = sinT[s * 32 + p];
                float x0 = acc[i][2 * jp], x1 = acc[i][2 * jp + 1];
                o8[2 * jp]     = f2bf((x0 * cc - x1 * ss) * qsc);
                o8[2 * jp + 1] = f2bf((x0 * ss + x1 * cc) * qsc);
            }
            unsigned short* dst = C + (((long)b * HEADS + h) * SEQ + s) * 64 + d;
            *(bf16x8*)dst = *(bf16x8*)o8;
        }
    } else {  // MODE 3: V transposed bf16 [b][h][d][SEQ]
        unsigned short* C = (unsigned short*)Cv;
        const int h = cb >> 6, d = cb & 63;
        const int mrow = m0 + ty * 8;
        const int b = mrow >> 11, sL = mrow & (SEQ - 1);
#pragma unroll
        for (int j = 0; j < 8; j++) {
            unsigned short o8[8];
#pragma unroll
            for (int i = 0; i < 8; i++) o8[i] = f2bf(acc[i][j]);
            unsigned short* dst = C + (((long)b * HEADS + h) * 64 + d + j) * SEQ + sL;
            *(bf16x8*)dst = *(bf16x8*)o8;
        }
    }
}

// ---------------------------------------------------------------------------
// bf16 MFMA flash attention.  Grid (S/64, B*NH), 256 thr = 4 waves.
// Block: 64 q-rows; wave w owns q-rows [w*16, w*16+16).  KV tile = 64.
// Q [b][h][S][64] bf16 (pre-scaled by 1/8);  K [b][hk][S][64] bf16;
// VT [b][hk][64][S] bf16;  O fp32 [B*S][2048].
// QK^T: A=Q frag (regs), B=K frag (LDS).  S-tile C-layout: row=q, col=k.
// PV computed as O^T = V^T · P^T: A=V^T frag, B=P frag (per-wave LDS).
// All LDS rows stride 144B -> conflict-free b128 access.
// ---------------------------------------------------------------------------
__global__ __launch_bounds__(256) void attn_mfma(const unsigned short* __restrict__ Q,
                                                 const unsigned short* __restrict__ K,
                                                 const unsigned short* __restrict__ VT,
                                                 float* __restrict__ O) {
    __shared__ __align__(16) unsigned short Kl[64 * 72];
    __shared__ __align__(16) unsigned short Vl[64 * 72];
    __shared__ __align__(16) unsigned short Pl[4][16 * 72];
    __shared__ float Aux[4][16];

    const int t = threadIdx.x, w = t >> 6, ln = t & 63;
    const int lo = ln & 15, hi = ln >> 4;
    const int qb_ = blockIdx.x, bh = blockIdx.y;
    const int b = bh >> 5, h = bh & 31, hk = h >> 2;
    const int q0 = qb_ * 64;

    const unsigned short* qp = Q + (((long)b * NH + h) * SEQ + q0 + w * 16) * 64;
    const unsigned short* kp = K + ((long)b * NKV + hk) * (long)SEQ * 64;
    const unsigned short* vp = VT + ((long)b * NKV + hk) * (long)HD * SEQ;

    // Q fragments: A[m=q][k=d]: lane: q=lo, d = dc*32 + hi*8 + j
    bf16x8 qf0 = *(const bf16x8*)(qp + lo * 64 + hi * 8);
    bf16x8 qf1 = *(const bf16x8*)(qp + lo * 64 + 32 + hi * 8);

    f32x4 acc[4];
    float m[4], l4[4];
#pragma unroll
    for (int i = 0; i < 4; i++) {
        acc[i] = (f32x4){0.f, 0.f, 0.f, 0.f};
        m[i] = -1e30f; l4[i] = 0.f;
    }

    const int rL  = ln >> 3;          // staging: local row 0..7
    const int cc8 = (ln & 7) * 8;     // 16B chunk within 128B row
    const int row0 = w * 8 + rL;      // this thread stages rows row0, row0+32

    const int nt = qb_ + 1;
    for (int kt = 0; kt < nt; kt++) {
        const int k0 = kt * 64;
        // issue global loads early (hide under barrier wait)
        bf16x8 kr0 = *(const bf16x8*)(kp + (long)(k0 + row0) * 64 + cc8);
        bf16x8 kr1 = *(const bf16x8*)(kp + (long)(k0 + 32 + row0) * 64 + cc8);
        bf16x8 vr0 = *(const bf16x8*)(vp + (long)row0 * SEQ + k0 + cc8);
        bf16x8 vr1 = *(const bf16x8*)(vp + (long)(32 + row0) * SEQ + k0 + cc8);
        __syncthreads();   // prev iteration's LDS reads complete
        *(bf16x8*)&Kl[row0 * 72 + cc8]        = kr0;
        *(bf16x8*)&Kl[(row0 + 32) * 72 + cc8] = kr1;
        *(bf16x8*)&Vl[row0 * 72 + cc8]        = vr0;
        *(bf16x8*)&Vl[(row0 + 32) * 72 + cc8] = vr1;
        __syncthreads();   // staging visible

        // ---- QK^T: 4 k-subtiles of 16, each D=64 via 2 MFMAs
        f32x4 sc[4];
#pragma unroll
        for (int k16 = 0; k16 < 4; k16++) {
            bf16x8 kf0 = *(const bf16x8*)&Kl[(k16 * 16 + lo) * 72 + hi * 8];
            bf16x8 kf1 = *(const bf16x8*)&Kl[(k16 * 16 + lo) * 72 + 32 + hi * 8];
            f32x4 z = {0.f, 0.f, 0.f, 0.f};
            z = __builtin_amdgcn_mfma_f32_16x16x32_bf16(qf0, kf0, z, 0, 0, 0);
            sc[k16] = __builtin_amdgcn_mfma_f32_16x16x32_bf16(qf1, kf1, z, 0, 0, 0);
        }

        // ---- online softmax.  Lane holds S[q=hi*4+rg][k=k16*16+lo]
        float pv[4][4];
        float alpha[4];
#pragma unroll
        for (int rg = 0; rg < 4; rg++) {
            int qg = q0 + w * 16 + hi * 4 + rg;
            float mx = -1e30f;
#pragma unroll
            for (int k16 = 0; k16 < 4; k16++) {
                float v = sc[k16][rg];
                v = (k0 + k16 * 16 + lo <= qg) ? v : -1e30f;
                pv[k16][rg] = v;
                mx = fmaxf(mx, v);
            }
            mx = fmaxf(mx, __shfl_xor(mx, 1));
            mx = fmaxf(mx, __shfl_xor(mx, 2));
            mx = fmaxf(mx, __shfl_xor(mx, 4));
            mx = fmaxf(mx, __shfl_xor(mx, 8));
            float mn = fmaxf(m[rg], mx);
            alpha[rg] = __expf(m[rg] - mn);
            m[rg] = mn;
            float ps = 0.f;
#pragma unroll
            for (int k16 = 0; k16 < 4; k16++) {
                float e = __expf(pv[k16][rg] - mn);
                pv[k16][rg] = e;
                ps += e;
            }
            ps += __shfl_xor(ps, 1);
            ps += __shfl_xor(ps, 2);
            ps += __shfl_xor(ps, 4);
            ps += __shfl_xor(ps, 8);
            l4[rg] = l4[rg] * alpha[rg] + ps;
        }

        // ---- P -> per-wave LDS (bf16, packed pair stores from even lanes)
        char* plb = (char*)&Pl[w][0];
#pragma unroll
        for (int rg = 0; rg < 4; rg++)
#pragma unroll
            for (int k16 = 0; k16 < 4; k16++) {
                float other = __shfl_xor(pv[k16][rg], 1);
                unsigned int pk = (unsigned int)f2bf(pv[k16][rg]) |
                                  ((unsigned int)f2bf(other) << 16);
                if ((lo & 1) == 0)
                    *(unsigned int*)(plb + (hi * 4 + rg) * 144 + (k16 * 16 + lo) * 2) = pk;
            }
        if (lo == 0) {
#pragma unroll
            for (int rg = 0; rg < 4; rg++) Aux[w][hi * 4 + rg] = alpha[rg];
        }
        // wave-private LDS: same-wave DS ops are ordered; no barrier needed
        float aq = Aux[w][lo];
#pragma unroll
        for (int dt = 0; dt < 4; dt++) {
            acc[dt][0] *= aq; acc[dt][1] *= aq;
            acc[dt][2] *= aq; acc[dt][3] *= aq;
        }

        // ---- PV:  O^T[d][q] += V^T[d][k] P^T[k][q]
        bf16x8 pf0 = *(const bf16x8*)&Pl[w][lo * 72 + hi * 8];        // P[q=lo][k=hi*8+j]
        bf16x8 pf1 = *(const bf16x8*)&Pl[w][lo * 72 + 32 + hi * 8];   // k+32
#pragma unroll
        for (int dt = 0; dt < 4; dt++) {
            bf16x8 vf0 = *(const bf16x8*)&Vl[(dt * 16 + lo) * 72 + hi * 8];
            bf16x8 vf1 = *(const bf16x8*)&Vl[(dt * 16 + lo) * 72 + 32 + hi * 8];
            acc[dt] = __builtin_amdgcn_mfma_f32_16x16x32_bf16(vf0, pf0, acc[dt], 0, 0, 0);
            acc[dt] = __builtin_amdgcn_mfma_f32_16x16x32_bf16(vf1, pf1, acc[dt], 0, 0, 0);
        }
    }

    // ---- epilogue: O^T lane holds d = dt*16 + hi*4 + rg, q = lo
    if (lo == 0) {
#pragma unroll
        for (int rg = 0; rg < 4; rg++) Aux[w][hi * 4 + rg] = l4[rg];
    }
    float linv = 1.f / Aux[w][lo];
    int qg = q0 + w * 16 + lo;
    float* dst = O + ((long)(b * SEQ + qg)) * (NH * HD) + h * 64 + hi * 4;
#pragma unroll
    for (int dt = 0; dt < 4; dt++) {
        float4 o;
        o.x = acc[dt][0] * linv; o.y = acc[dt][1] * linv;
        o.z = acc[dt][2] * linv; o.w = acc[dt][3] * linv;
        *(float4*)(dst + dt * 16) = o;
    }
}

// ---------------------------------------------------------------------------
extern "C" void kernel_launch(void* const* d_in, const int* in_sizes, int n_in,
                              void* d_out, int out_size, void* d_ws, size_t ws_size,
                              hipStream_t stream) {
    const float* x  = (const float*)d_in[0];
    const float* wq = (const float*)d_in[1];
    const float* wk = (const float*)d_in[2];
    const float* wv = (const float*)d_in[3];
    const float* wo = (const float*)d_in[4];
    float* out = (float*)d_out;

    char* ws = (char*)d_ws;
    float* cosT = (float*)ws;                                   // 256 KB
    float* sinT = (float*)(ws + (256 << 10));                   // 256 KB
    unsigned short* qb = (unsigned short*)(ws + (512 << 10));   // 16 MB bf16 [2][32][S][64]
    unsigned short* kb = qb + (long)2 * NH * SEQ * HD;          // 4 MB  bf16 [2][8][S][64]
    unsigned short* vt = kb + (long)2 * NKV * SEQ * HD;         // 4 MB  bf16 [2][8][64][S]
    float* ao = (float*)(vt + (long)2 * NKV * SEQ * HD);        // 32 MB fp32 [B*S][2048]

    rope_table_k<<<SEQ * 32 / 256, 256, 0, stream>>>(cosT, sinT);

    // QKV projections -> bf16 headed layouts (Q scaled 1/8, V transposed)
    gemm128<2, NH> <<<dim3(2048 / 128, MROWS / 128), 256, 0, stream>>>(
        x, wq, qb, MROWS, 2048, DIM, cosT, sinT);
    gemm128<2, NKV><<<dim3(512 / 128, MROWS / 128), 256, 0, stream>>>(
        x, wk, kb, MROWS, 512, DIM, cosT, sinT);
    gemm128<3, NKV><<<dim3(512 / 128, MROWS / 128), 256, 0, stream>>>(
        x, wv, vt, MROWS, 512, DIM, nullptr, nullptr);

    // causal GQA flash attention (bf16 MFMA)
    attn_mfma<<<dim3(SEQ / 64, 2 * NH), 256, 0, stream>>>(qb, kb, vt, ao);

    // output projection (fp32)
    gemm128<0, 1><<<dim3(2048 / 128, MROWS / 128), 256, 0, stream>>>(
        ao, wo, out, MROWS, 2048, DIM, nullptr, nullptr);
}

// Round 8
// 608.906 us; speedup vs baseline: 4.9111x; 3.0566x over previous
//
#include <hip/hip_runtime.h>
#include <hip/hip_bf16.h>
#include <math.h>

// Problem constants (fixed by reference)
#define NH 32
#define NKV 8
#define HD 64
constexpr int SEQ  = 2048;
constexpr int DIM  = 2048;
constexpr int MROWS = 2 * SEQ;   // B*S = 4096

typedef __attribute__((ext_vector_type(8))) short bf16x8;   // 8 bf16 = 4 VGPRs (MFMA A/B frag)
typedef __attribute__((ext_vector_type(4))) float f32x4;    // MFMA C/D frag

__device__ __forceinline__ unsigned short f2bf(float f) {   // RNE float->bf16
    unsigned int u = __float_as_uint(f);
    u += 0x7fffu + ((u >> 16) & 1u);
    return (unsigned short)(u >> 16);
}
__device__ __forceinline__ float bf2f(unsigned short h) {
    return __uint_as_float((unsigned int)h << 16);
}

// async global->LDS, 16B per lane.  LDS dst must be wave-uniform (HW adds lane*16).
__device__ __forceinline__ void gload16(const void* g, void* l) {
    __builtin_amdgcn_global_load_lds(
        (const __attribute__((address_space(1))) unsigned int*)g,
        (__attribute__((address_space(3))) unsigned int*)l, 16, 0, 0);
}

// ---------------------------------------------------------------------------
// RoPE cos/sin tables: [S][32].
// ---------------------------------------------------------------------------
__global__ __launch_bounds__(256) void rope_table_k(float* __restrict__ cosT,
                                                    float* __restrict__ sinT) {
    int i = blockIdx.x * 256 + threadIdx.x;   // i < SEQ*32
    int s = i >> 5, p = i & 31;
    float inv = (float)pow(10000.0, -(double)p / 32.0);
    float a = (float)s * inv;
    cosT[i] = cosf(a);
    sinT[i] = sinf(a);
}

// ---------------------------------------------------------------------------
// cast fp32 -> bf16, 8 elems/thread
// ---------------------------------------------------------------------------
__global__ __launch_bounds__(256) void cast_x_k(const float* __restrict__ X,
                                                unsigned short* __restrict__ Xb) {
    long i = ((long)blockIdx.x * 256 + threadIdx.x) * 8;
    float4 a = *(const float4*)(X + i);
    float4 b = *(const float4*)(X + i + 4);
    ushort4 o0, o1;
    o0.x = f2bf(a.x); o0.y = f2bf(a.y); o0.z = f2bf(a.z); o0.w = f2bf(a.w);
    o1.x = f2bf(b.x); o1.y = f2bf(b.y); o1.z = f2bf(b.z); o1.w = f2bf(b.w);
    *(ushort4*)(Xb + i)     = o0;
    *(ushort4*)(Xb + i + 4) = o1;
}

// ---------------------------------------------------------------------------
// transpose+cast: W fp32 [DIM][Nw] -> T bf16 [Nw][DIM] (row stride DIM)
// ---------------------------------------------------------------------------
__global__ __launch_bounds__(256) void tcast_k(const float* __restrict__ W,
                                               unsigned short* __restrict__ T,
                                               int Nw) {
    __shared__ float Ts[32][36];
    const int t = threadIdx.x;
    const int k0 = blockIdx.y * 32, n0 = blockIdx.x * 32;
    const int r = t >> 3, c4 = (t & 7) * 4;
    *(float4*)&Ts[r][c4] = *(const float4*)(W + (long)(k0 + r) * Nw + n0 + c4);
    __syncthreads();
    ushort4 o;
    o.x = f2bf(Ts[c4 + 0][r]); o.y = f2bf(Ts[c4 + 1][r]);
    o.z = f2bf(Ts[c4 + 2][r]); o.w = f2bf(Ts[c4 + 3][r]);
    *(ushort4*)(T + (long)(n0 + r) * DIM + k0 + c4) = o;
}

// transpose + split into hi/lo bf16 (for fp32-accuracy wo GEMM)
__global__ __launch_bounds__(256) void tcast_hilo_k(const float* __restrict__ W,
                                                    unsigned short* __restrict__ Th,
                                                    unsigned short* __restrict__ Tl) {
    __shared__ float Ts[32][36];
    const int t = threadIdx.x;
    const int k0 = blockIdx.y * 32, n0 = blockIdx.x * 32;
    const int r = t >> 3, c4 = (t & 7) * 4;
    *(float4*)&Ts[r][c4] = *(const float4*)(W + (long)(k0 + r) * DIM + n0 + c4);
    __syncthreads();
    ushort4 oh, ol;
    float v0 = Ts[c4 + 0][r], v1 = Ts[c4 + 1][r], v2 = Ts[c4 + 2][r], v3 = Ts[c4 + 3][r];
    oh.x = f2bf(v0); oh.y = f2bf(v1); oh.z = f2bf(v2); oh.w = f2bf(v3);
    ol.x = f2bf(v0 - bf2f(oh.x)); ol.y = f2bf(v1 - bf2f(oh.y));
    ol.z = f2bf(v2 - bf2f(oh.z)); ol.w = f2bf(v3 - bf2f(oh.w));
    long o = (long)(n0 + r) * DIM + k0 + c4;
    *(ushort4*)(Th + o) = oh;
    *(ushort4*)(Tl + o) = ol;
}

// ---------------------------------------------------------------------------
// Fused QKV bf16 MFMA GEMM.  A bf16 [4096][2048]; Bt bf16 [3072][2048] (= W^T,
// rows: 0..2047 Q, 2048..2559 K, 2560..3071 V).  128x128 tile, BK=64, 4 waves.
// Epilogue per n-region: Q rope+1/8 -> qb; K rope -> kb; V -> vt transposed.
// ---------------------------------------------------------------------------
__global__ __launch_bounds__(256) void gemm_qkv(const unsigned short* __restrict__ A,
                                                const unsigned short* __restrict__ Bt,
                                                unsigned short* __restrict__ qb,
                                                unsigned short* __restrict__ kb,
                                                unsigned short* __restrict__ vt,
                                                const float* __restrict__ cosT,
                                                const float* __restrict__ sinT) {
    constexpr int K = DIM;
    __shared__ unsigned short Als[128 * 64];
    __shared__ unsigned short Bls[128 * 64];

    const int t = threadIdx.x, w = t >> 6, ln = t & 63;
    const int lo = ln & 15, hi = ln >> 4;
    const int wr = w >> 1, wc = w & 1;
    const int m0 = blockIdx.y * 128, n0 = blockIdx.x * 128;

    f32x4 acc[4][4];
#pragma unroll
    for (int i = 0; i < 4; i++)
#pragma unroll
        for (int j = 0; j < 4; j++) acc[i][j] = (f32x4){0.f, 0.f, 0.f, 0.f};

    const int srow = ln >> 3, scol = (ln & 7) * 8;
    const unsigned short* Ab = A  + (long)(m0 + w * 32 + srow) * K + scol;
    const unsigned short* Bb = Bt + (long)(n0 + w * 32 + srow) * K + scol;
    unsigned short* Alw = &Als[w * 2048];
    unsigned short* Blw = &Bls[w * 2048];

    for (int k0 = 0; k0 < K; k0 += 64) {
        __syncthreads();
#pragma unroll
        for (int it = 0; it < 4; it++) {
            gload16(Ab + (long)it * 8 * K + k0, Alw + it * 512);
            gload16(Bb + (long)it * 8 * K + k0, Blw + it * 512);
        }
        __syncthreads();

        bf16x8 af[4][2], bfr[4][2];
#pragma unroll
        for (int i = 0; i < 4; i++) {
            af[i][0]  = *(const bf16x8*)&Als[(wr * 64 + i * 16 + lo) * 64 + hi * 8];
            af[i][1]  = *(const bf16x8*)&Als[(wr * 64 + i * 16 + lo) * 64 + 32 + hi * 8];
            bfr[i][0] = *(const bf16x8*)&Bls[(wc * 64 + i * 16 + lo) * 64 + hi * 8];
            bfr[i][1] = *(const bf16x8*)&Bls[(wc * 64 + i * 16 + lo) * 64 + 32 + hi * 8];
        }
#pragma unroll
        for (int i = 0; i < 4; i++)
#pragma unroll
            for (int j = 0; j < 4; j++) {
                acc[i][j] = __builtin_amdgcn_mfma_f32_16x16x32_bf16(af[i][0], bfr[j][0], acc[i][j], 0, 0, 0);
                acc[i][j] = __builtin_amdgcn_mfma_f32_16x16x32_bf16(af[i][1], bfr[j][1], acc[i][j], 0, 0, 0);
            }
    }

    // ---- epilogue.  C elem: m = m0+wr*64+i*16+hi*4+r,  n = n0+wc*64+j*16+lo
    const int nb = n0 + wc * 64;
    const int mb = m0 + wr * 64;
    if (n0 < 2048) {          // Q: rope + 1/8 scale
#pragma unroll
        for (int j = 0; j < 4; j++) {
            const int n = nb + j * 16 + lo;
            const int h = n >> 6, d = n & 63, p = d >> 1;
            const int odd = d & 1;
#pragma unroll
            for (int i = 0; i < 4; i++)
#pragma unroll
                for (int r = 0; r < 4; r++) {
                    int mg = mb + i * 16 + hi * 4 + r;
                    int b = mg >> 11, s = mg & (SEQ - 1);
                    float v = acc[i][j][r];
                    float part = __shfl_xor(v, 1);
                    float c = cosT[s * 32 + p], sn = sinT[s * 32 + p];
                    float o = odd ? (part * sn + v * c) : (v * c - part * sn);
                    qb[(((long)b * NH + h) * SEQ + s) * 64 + d] = f2bf(o * 0.125f);
                }
        }
    } else if (n0 < 2560) {   // K: rope
#pragma unroll
        for (int j = 0; j < 4; j++) {
            const int n = nb + j * 16 + lo - 2048;
            const int h = n >> 6, d = n & 63, p = d >> 1;
            const int odd = d & 1;
#pragma unroll
            for (int i = 0; i < 4; i++)
#pragma unroll
                for (int r = 0; r < 4; r++) {
                    int mg = mb + i * 16 + hi * 4 + r;
                    int b = mg >> 11, s = mg & (SEQ - 1);
                    float v = acc[i][j][r];
                    float part = __shfl_xor(v, 1);
                    float c = cosT[s * 32 + p], sn = sinT[s * 32 + p];
                    float o = odd ? (part * sn + v * c) : (v * c - part * sn);
                    kb[(((long)b * NKV + h) * SEQ + s) * 64 + d] = f2bf(o);
                }
        }
    } else {                  // V: transposed store [b][hk][64][S]
#pragma unroll
        for (int j = 0; j < 4; j++) {
            const int n = nb + j * 16 + lo - 2560;
            const int h = n >> 6, d = n & 63;
#pragma unroll
            for (int i = 0; i < 4; i++) {
                int mg = mb + i * 16 + hi * 4;
                int b = mg >> 11, s = mg & (SEQ - 1);
                ushort4 pk;
                pk.x = f2bf(acc[i][j][0]); pk.y = f2bf(acc[i][j][1]);
                pk.z = f2bf(acc[i][j][2]); pk.w = f2bf(acc[i][j][3]);
                *(ushort4*)&vt[(((long)b * NKV + h) * 64 + d) * SEQ + s] = pk;
            }
        }
    }
}

// ---------------------------------------------------------------------------
// wo GEMM, split-bf16 (hi/lo) for fp32-class accuracy: C = A@B via
// Ah*Bh + Ah*Bl + Al*Bh.  A [4096][2048] hi/lo bf16; B^T [2048][2048] hi/lo.
// 128x128 tile, BK=32, 4 waves.
// ---------------------------------------------------------------------------
__global__ __launch_bounds__(256) void gemm_wo(const unsigned short* __restrict__ Ah_,
                                               const unsigned short* __restrict__ Al_,
                                               const unsigned short* __restrict__ Bh_,
                                               const unsigned short* __restrict__ Bl_,
                                               float* __restrict__ C) {
    constexpr int K = DIM, N = DIM;
    __shared__ unsigned short sAh[128 * 32], sAl[128 * 32];
    __shared__ unsigned short sBh[128 * 32], sBl[128 * 32];

    const int t = threadIdx.x, w = t >> 6, ln = t & 63;
    const int lo = ln & 15, hi = ln >> 4;
    const int wr = w >> 1, wc = w & 1;
    const int m0 = blockIdx.y * 128, n0 = blockIdx.x * 128;

    f32x4 acc[4][4];
#pragma unroll
    for (int i = 0; i < 4; i++)
#pragma unroll
        for (int j = 0; j < 4; j++) acc[i][j] = (f32x4){0.f, 0.f, 0.f, 0.f};

    const int srow = ln >> 2, scol = (ln & 3) * 8;
    const unsigned short* pAh = Ah_ + (long)(m0 + w * 32 + srow) * K + scol;
    const unsigned short* pAl = Al_ + (long)(m0 + w * 32 + srow) * K + scol;
    const unsigned short* pBh = Bh_ + (long)(n0 + w * 32 + srow) * K + scol;
    const unsigned short* pBl = Bl_ + (long)(n0 + w * 32 + srow) * K + scol;

    for (int k0 = 0; k0 < K; k0 += 32) {
        __syncthreads();
#pragma unroll
        for (int it = 0; it < 2; it++) {
            long go = (long)it * 16 * K + k0;
            int lofs = w * 1024 + it * 512;
            gload16(pAh + go, &sAh[lofs]);
            gload16(pAl + go, &sAl[lofs]);
            gload16(pBh + go, &sBh[lofs]);
            gload16(pBl + go, &sBl[lofs]);
        }
        __syncthreads();

        bf16x8 ah[4], al[4], bh[4], bl[4];
#pragma unroll
        for (int i = 0; i < 4; i++) {
            ah[i] = *(const bf16x8*)&sAh[(wr * 64 + i * 16 + lo) * 32 + hi * 8];
            al[i] = *(const bf16x8*)&sAl[(wr * 64 + i * 16 + lo) * 32 + hi * 8];
            bh[i] = *(const bf16x8*)&sBh[(wc * 64 + i * 16 + lo) * 32 + hi * 8];
            bl[i] = *(const bf16x8*)&sBl[(wc * 64 + i * 16 + lo) * 32 + hi * 8];
        }
#pragma unroll
        for (int i = 0; i < 4; i++)
#pragma unroll
            for (int j = 0; j < 4; j++) {
                acc[i][j] = __builtin_amdgcn_mfma_f32_16x16x32_bf16(ah[i], bh[j], acc[i][j], 0, 0, 0);
                acc[i][j] = __builtin_amdgcn_mfma_f32_16x16x32_bf16(ah[i], bl[j], acc[i][j], 0, 0, 0);
                acc[i][j] = __builtin_amdgcn_mfma_f32_16x16x32_bf16(al[i], bh[j], acc[i][j], 0, 0, 0);
            }
    }

#pragma unroll
    for (int j = 0; j < 4; j++) {
        const int n = n0 + wc * 64 + j * 16 + lo;
#pragma unroll
        for (int i = 0; i < 4; i++)
#pragma unroll
            for (int r = 0; r < 4; r++)
                C[(long)(m0 + wr * 64 + i * 16 + hi * 4 + r) * N + n] = acc[i][j][r];
    }
}

// ---------------------------------------------------------------------------
// bf16 MFMA flash attention (validated round 3).  Epilogue now emits O as
// hi/lo bf16 pair for the split wo GEMM.
// ---------------------------------------------------------------------------
__global__ __launch_bounds__(256) void attn_mfma(const unsigned short* __restrict__ Q,
                                                 const unsigned short* __restrict__ K,
                                                 const unsigned short* __restrict__ VT,
                                                 unsigned short* __restrict__ Oh,
                                                 unsigned short* __restrict__ Ol) {
    __shared__ __align__(16) unsigned short Kl[64 * 72];
    __shared__ __align__(16) unsigned short Vl[64 * 72];
    __shared__ __align__(16) unsigned short Pl[4][16 * 72];
    __shared__ float Aux[4][16];

    const int t = threadIdx.x, w = t >> 6, ln = t & 63;
    const int lo = ln & 15, hi = ln >> 4;
    const int qb_ = blockIdx.x, bh = blockIdx.y;
    const int b = bh >> 5, h = bh & 31, hk = h >> 2;
    const int q0 = qb_ * 64;

    const unsigned short* qp = Q + (((long)b * NH + h) * SEQ + q0 + w * 16) * 64;
    const unsigned short* kp = K + ((long)b * NKV + hk) * (long)SEQ * 64;
    const unsigned short* vp = VT + ((long)b * NKV + hk) * (long)HD * SEQ;

    bf16x8 qf0 = *(const bf16x8*)(qp + lo * 64 + hi * 8);
    bf16x8 qf1 = *(const bf16x8*)(qp + lo * 64 + 32 + hi * 8);

    f32x4 acc[4];
    float m[4], l4[4];
#pragma unroll
    for (int i = 0; i < 4; i++) {
        acc[i] = (f32x4){0.f, 0.f, 0.f, 0.f};
        m[i] = -1e30f; l4[i] = 0.f;
    }

    const int rL  = ln >> 3;
    const int cc8 = (ln & 7) * 8;
    const int row0 = w * 8 + rL;

    const int nt = qb_ + 1;
    for (int kt = 0; kt < nt; kt++) {
        const int k0 = kt * 64;
        bf16x8 kr0 = *(const bf16x8*)(kp + (long)(k0 + row0) * 64 + cc8);
        bf16x8 kr1 = *(const bf16x8*)(kp + (long)(k0 + 32 + row0) * 64 + cc8);
        bf16x8 vr0 = *(const bf16x8*)(vp + (long)row0 * SEQ + k0 + cc8);
        bf16x8 vr1 = *(const bf16x8*)(vp + (long)(32 + row0) * SEQ + k0 + cc8);
        __syncthreads();
        *(bf16x8*)&Kl[row0 * 72 + cc8]        = kr0;
        *(bf16x8*)&Kl[(row0 + 32) * 72 + cc8] = kr1;
        *(bf16x8*)&Vl[row0 * 72 + cc8]        = vr0;
        *(bf16x8*)&Vl[(row0 + 32) * 72 + cc8] = vr1;
        __syncthreads();

        f32x4 sc[4];
#pragma unroll
        for (int k16 = 0; k16 < 4; k16++) {
            bf16x8 kf0 = *(const bf16x8*)&Kl[(k16 * 16 + lo) * 72 + hi * 8];
            bf16x8 kf1 = *(const bf16x8*)&Kl[(k16 * 16 + lo) * 72 + 32 + hi * 8];
            f32x4 z = {0.f, 0.f, 0.f, 0.f};
            z = __builtin_amdgcn_mfma_f32_16x16x32_bf16(qf0, kf0, z, 0, 0, 0);
            sc[k16] = __builtin_amdgcn_mfma_f32_16x16x32_bf16(qf1, kf1, z, 0, 0, 0);
        }

        float pv[4][4];
        float alpha[4];
#pragma unroll
        for (int rg = 0; rg < 4; rg++) {
            int qg = q0 + w * 16 + hi * 4 + rg;
            float mx = -1e30f;
#pragma unroll
            for (int k16 = 0; k16 < 4; k16++) {
                float v = sc[k16][rg];
                v = (k0 + k16 * 16 + lo <= qg) ? v : -1e30f;
                pv[k16][rg] = v;
                mx = fmaxf(mx, v);
            }
            mx = fmaxf(mx, __shfl_xor(mx, 1));
            mx = fmaxf(mx, __shfl_xor(mx, 2));
            mx = fmaxf(mx, __shfl_xor(mx, 4));
            mx = fmaxf(mx, __shfl_xor(mx, 8));
            float mn = fmaxf(m[rg], mx);
            alpha[rg] = __expf(m[rg] - mn);
            m[rg] = mn;
            float ps = 0.f;
#pragma unroll
            for (int k16 = 0; k16 < 4; k16++) {
                float e = __expf(pv[k16][rg] - mn);
                pv[k16][rg] = e;
                ps += e;
            }
            ps += __shfl_xor(ps, 1);
            ps += __shfl_xor(ps, 2);
            ps += __shfl_xor(ps, 4);
            ps += __shfl_xor(ps, 8);
            l4[rg] = l4[rg] * alpha[rg] + ps;
        }

        char* plb = (char*)&Pl[w][0];
#pragma unroll
        for (int rg = 0; rg < 4; rg++)
#pragma unroll
            for (int k16 = 0; k16 < 4; k16++) {
                float other = __shfl_xor(pv[k16][rg], 1);
                unsigned int pk = (unsigned int)f2bf(pv[k16][rg]) |
                                  ((unsigned int)f2bf(other) << 16);
                if ((lo & 1) == 0)
                    *(unsigned int*)(plb + (hi * 4 + rg) * 144 + (k16 * 16 + lo) * 2) = pk;
            }
        if (lo == 0) {
#pragma unroll
            for (int rg = 0; rg < 4; rg++) Aux[w][hi * 4 + rg] = alpha[rg];
        }
        float aq = Aux[w][lo];
#pragma unroll
        for (int dt = 0; dt < 4; dt++) {
            acc[dt][0] *= aq; acc[dt][1] *= aq;
            acc[dt][2] *= aq; acc[dt][3] *= aq;
        }

        bf16x8 pf0 = *(const bf16x8*)&Pl[w][lo * 72 + hi * 8];
        bf16x8 pf1 = *(const bf16x8*)&Pl[w][lo * 72 + 32 + hi * 8];
#pragma unroll
        for (int dt = 0; dt < 4; dt++) {
            bf16x8 vf0 = *(const bf16x8*)&Vl[(dt * 16 + lo) * 72 + hi * 8];
            bf16x8 vf1 = *(const bf16x8*)&Vl[(dt * 16 + lo) * 72 + 32 + hi * 8];
            acc[dt] = __builtin_amdgcn_mfma_f32_16x16x32_bf16(vf0, pf0, acc[dt], 0, 0, 0);
            acc[dt] = __builtin_amdgcn_mfma_f32_16x16x32_bf16(vf1, pf1, acc[dt], 0, 0, 0);
        }
    }

    if (lo == 0) {
#pragma unroll
        for (int rg = 0; rg < 4; rg++) Aux[w][hi * 4 + rg] = l4[rg];
    }
    float linv = 1.f / Aux[w][lo];
    int qg = q0 + w * 16 + lo;
    long rowo = (long)(b * SEQ + qg) * (NH * HD) + h * 64;
#pragma unroll
    for (int dt = 0; dt < 4; dt++) {
        float o0 = acc[dt][0] * linv, o1 = acc[dt][1] * linv;
        float o2 = acc[dt][2] * linv, o3 = acc[dt][3] * linv;
        ushort4 hv, lv;
        hv.x = f2bf(o0); hv.y = f2bf(o1); hv.z = f2bf(o2); hv.w = f2bf(o3);
        lv.x = f2bf(o0 - bf2f(hv.x)); lv.y = f2bf(o1 - bf2f(hv.y));
        lv.z = f2bf(o2 - bf2f(hv.z)); lv.w = f2bf(o3 - bf2f(hv.w));
        *(ushort4*)&Oh[rowo + dt * 16 + hi * 4] = hv;
        *(ushort4*)&Ol[rowo + dt * 16 + hi * 4] = lv;
    }
}

// ---------------------------------------------------------------------------
extern "C" void kernel_launch(void* const* d_in, const int* in_sizes, int n_in,
                              void* d_out, int out_size, void* d_ws, size_t ws_size,
                              hipStream_t stream) {
    const float* x  = (const float*)d_in[0];
    const float* wq = (const float*)d_in[1];
    const float* wk = (const float*)d_in[2];
    const float* wv = (const float*)d_in[3];
    const float* wo = (const float*)d_in[4];
    float* out = (float*)d_out;

    char* ws = (char*)d_ws;
    long off = 0;
    float* cosT = (float*)(ws + off);                 off += (long)SEQ * 32 * 4;
    float* sinT = (float*)(ws + off);                 off += (long)SEQ * 32 * 4;
    unsigned short* xb    = (unsigned short*)(ws + off); off += (long)MROWS * DIM * 2;     // 16MB
    unsigned short* wqkvT = (unsigned short*)(ws + off); off += (long)3072 * DIM * 2;      // 12MB
    unsigned short* woTh  = (unsigned short*)(ws + off); off += (long)DIM * DIM * 2;       // 8MB
    unsigned short* woTl  = (unsigned short*)(ws + off); off += (long)DIM * DIM * 2;       // 8MB
    unsigned short* qb    = (unsigned short*)(ws + off); off += (long)2 * NH * SEQ * HD * 2;   // 16MB
    unsigned short* kb    = (unsigned short*)(ws + off); off += (long)2 * NKV * SEQ * HD * 2;  // 4MB
    unsigned short* vt    = (unsigned short*)(ws + off); off += (long)2 * NKV * SEQ * HD * 2;  // 4MB
    unsigned short* aoh   = (unsigned short*)(ws + off); off += (long)MROWS * DIM * 2;     // 16MB
    unsigned short* aol   = (unsigned short*)(ws + off); off += (long)MROWS * DIM * 2;     // 16MB

    rope_table_k<<<SEQ * 32 / 256, 256, 0, stream>>>(cosT, sinT);
    cast_x_k<<<MROWS * DIM / 2048, 256, 0, stream>>>(x, xb);
    tcast_k<<<dim3(64, 64), 256, 0, stream>>>(wq, wqkvT, 2048);
    tcast_k<<<dim3(16, 64), 256, 0, stream>>>(wk, wqkvT + (long)2048 * DIM, 512);
    tcast_k<<<dim3(16, 64), 256, 0, stream>>>(wv, wqkvT + (long)2560 * DIM, 512);
    tcast_hilo_k<<<dim3(64, 64), 256, 0, stream>>>(wo, woTh, woTl);

    // fused QKV projection (bf16 MFMA) with rope/scale/V-transpose epilogue
    gemm_qkv<<<dim3(3072 / 128, MROWS / 128), 256, 0, stream>>>(
        xb, wqkvT, qb, kb, vt, cosT, sinT);

    // causal GQA flash attention (bf16 MFMA) -> hi/lo bf16 output
    attn_mfma<<<dim3(SEQ / 64, 2 * NH), 256, 0, stream>>>(qb, kb, vt, aoh, aol);

    // output projection, split-bf16 (fp32-class accuracy)
    gemm_wo<<<dim3(DIM / 128, MROWS / 128), 256, 0, stream>>>(
        aoh, aol, woTh, woTl, out);
}

// Round 9
// 469.469 us; speedup vs baseline: 6.3697x; 1.2970x over previous
//
#include <hip/hip_runtime.h>
#include <hip/hip_bf16.h>
#include <math.h>

// Problem constants (fixed by reference)
#define NH 32
#define NKV 8
#define HD 64
constexpr int SEQ  = 2048;
constexpr int DIM  = 2048;
constexpr int MROWS = 2 * SEQ;   // B*S = 4096

typedef __attribute__((ext_vector_type(8))) short bf16x8;   // 8 bf16 = 4 VGPRs (MFMA A/B frag)
typedef __attribute__((ext_vector_type(4))) float f32x4;    // MFMA C/D frag

__device__ __forceinline__ unsigned short f2bf(float f) {   // RNE float->bf16
    unsigned int u = __float_as_uint(f);
    u += 0x7fffu + ((u >> 16) & 1u);
    return (unsigned short)(u >> 16);
}
__device__ __forceinline__ float bf2f(unsigned short h) {
    return __uint_as_float((unsigned int)h << 16);
}

// async global->LDS, 16B per lane.  LDS dst must be wave-uniform (HW adds lane*16).
__device__ __forceinline__ void gload16(const void* g, void* l) {
    __builtin_amdgcn_global_load_lds(
        (const __attribute__((address_space(1))) unsigned int*)g,
        (__attribute__((address_space(3))) unsigned int*)l, 16, 0, 0);
}

// ---------------------------------------------------------------------------
// RoPE cos/sin tables: [S][32].
// ---------------------------------------------------------------------------
__global__ __launch_bounds__(256) void rope_table_k(float* __restrict__ cosT,
                                                    float* __restrict__ sinT) {
    int i = blockIdx.x * 256 + threadIdx.x;   // i < SEQ*32
    int s = i >> 5, p = i & 31;
    float inv = (float)pow(10000.0, -(double)p / 32.0);
    float a = (float)s * inv;
    cosT[i] = cosf(a);
    sinT[i] = sinf(a);
}

// ---------------------------------------------------------------------------
// cast fp32 -> bf16, 8 elems/thread
// ---------------------------------------------------------------------------
__global__ __launch_bounds__(256) void cast_x_k(const float* __restrict__ X,
                                                unsigned short* __restrict__ Xb) {
    long i = ((long)blockIdx.x * 256 + threadIdx.x) * 8;
    float4 a = *(const float4*)(X + i);
    float4 b = *(const float4*)(X + i + 4);
    ushort4 o0, o1;
    o0.x = f2bf(a.x); o0.y = f2bf(a.y); o0.z = f2bf(a.z); o0.w = f2bf(a.w);
    o1.x = f2bf(b.x); o1.y = f2bf(b.y); o1.z = f2bf(b.z); o1.w = f2bf(b.w);
    *(ushort4*)(Xb + i)     = o0;
    *(ushort4*)(Xb + i + 4) = o1;
}

// ---------------------------------------------------------------------------
// transpose+cast: W fp32 [DIM][Nw] -> T bf16 [Nw][DIM] (row stride DIM)
// ---------------------------------------------------------------------------
__global__ __launch_bounds__(256) void tcast_k(const float* __restrict__ W,
                                               unsigned short* __restrict__ T,
                                               int Nw) {
    __shared__ float Ts[32][36];
    const int t = threadIdx.x;
    const int k0 = blockIdx.y * 32, n0 = blockIdx.x * 32;
    const int r = t >> 3, c4 = (t & 7) * 4;
    *(float4*)&Ts[r][c4] = *(const float4*)(W + (long)(k0 + r) * Nw + n0 + c4);
    __syncthreads();
    ushort4 o;
    o.x = f2bf(Ts[c4 + 0][r]); o.y = f2bf(Ts[c4 + 1][r]);
    o.z = f2bf(Ts[c4 + 2][r]); o.w = f2bf(Ts[c4 + 3][r]);
    *(ushort4*)(T + (long)(n0 + r) * DIM + k0 + c4) = o;
}

// transpose + split into hi/lo bf16 (for fp32-accuracy wo GEMM)
__global__ __launch_bounds__(256) void tcast_hilo_k(const float* __restrict__ W,
                                                    unsigned short* __restrict__ Th,
                                                    unsigned short* __restrict__ Tl) {
    __shared__ float Ts[32][36];
    const int t = threadIdx.x;
    const int k0 = blockIdx.y * 32, n0 = blockIdx.x * 32;
    const int r = t >> 3, c4 = (t & 7) * 4;
    *(float4*)&Ts[r][c4] = *(const float4*)(W + (long)(k0 + r) * DIM + n0 + c4);
    __syncthreads();
    ushort4 oh, ol;
    float v0 = Ts[c4 + 0][r], v1 = Ts[c4 + 1][r], v2 = Ts[c4 + 2][r], v3 = Ts[c4 + 3][r];
    oh.x = f2bf(v0); oh.y = f2bf(v1); oh.z = f2bf(v2); oh.w = f2bf(v3);
    ol.x = f2bf(v0 - bf2f(oh.x)); ol.y = f2bf(v1 - bf2f(oh.y));
    ol.z = f2bf(v2 - bf2f(oh.z)); ol.w = f2bf(v3 - bf2f(oh.w));
    long o = (long)(n0 + r) * DIM + k0 + c4;
    *(ushort4*)(Th + o) = oh;
    *(ushort4*)(Tl + o) = ol;
}

// ---------------------------------------------------------------------------
// Fused QKV bf16 MFMA GEMM.  (unchanged, validated round 8)
// ---------------------------------------------------------------------------
__global__ __launch_bounds__(256) void gemm_qkv(const unsigned short* __restrict__ A,
                                                const unsigned short* __restrict__ Bt,
                                                unsigned short* __restrict__ qb,
                                                unsigned short* __restrict__ kb,
                                                unsigned short* __restrict__ vt,
                                                const float* __restrict__ cosT,
                                                const float* __restrict__ sinT) {
    constexpr int K = DIM;
    __shared__ unsigned short Als[128 * 64];
    __shared__ unsigned short Bls[128 * 64];

    const int t = threadIdx.x, w = t >> 6, ln = t & 63;
    const int lo = ln & 15, hi = ln >> 4;
    const int wr = w >> 1, wc = w & 1;
    const int m0 = blockIdx.y * 128, n0 = blockIdx.x * 128;

    f32x4 acc[4][4];
#pragma unroll
    for (int i = 0; i < 4; i++)
#pragma unroll
        for (int j = 0; j < 4; j++) acc[i][j] = (f32x4){0.f, 0.f, 0.f, 0.f};

    const int srow = ln >> 3, scol = (ln & 7) * 8;
    const unsigned short* Ab = A  + (long)(m0 + w * 32 + srow) * K + scol;
    const unsigned short* Bb = Bt + (long)(n0 + w * 32 + srow) * K + scol;
    unsigned short* Alw = &Als[w * 2048];
    unsigned short* Blw = &Bls[w * 2048];

    for (int k0 = 0; k0 < K; k0 += 64) {
        __syncthreads();
#pragma unroll
        for (int it = 0; it < 4; it++) {
            gload16(Ab + (long)it * 8 * K + k0, Alw + it * 512);
            gload16(Bb + (long)it * 8 * K + k0, Blw + it * 512);
        }
        __syncthreads();

        bf16x8 af[4][2], bfr[4][2];
#pragma unroll
        for (int i = 0; i < 4; i++) {
            af[i][0]  = *(const bf16x8*)&Als[(wr * 64 + i * 16 + lo) * 64 + hi * 8];
            af[i][1]  = *(const bf16x8*)&Als[(wr * 64 + i * 16 + lo) * 64 + 32 + hi * 8];
            bfr[i][0] = *(const bf16x8*)&Bls[(wc * 64 + i * 16 + lo) * 64 + hi * 8];
            bfr[i][1] = *(const bf16x8*)&Bls[(wc * 64 + i * 16 + lo) * 64 + 32 + hi * 8];
        }
#pragma unroll
        for (int i = 0; i < 4; i++)
#pragma unroll
            for (int j = 0; j < 4; j++) {
                acc[i][j] = __builtin_amdgcn_mfma_f32_16x16x32_bf16(af[i][0], bfr[j][0], acc[i][j], 0, 0, 0);
                acc[i][j] = __builtin_amdgcn_mfma_f32_16x16x32_bf16(af[i][1], bfr[j][1], acc[i][j], 0, 0, 0);
            }
    }

    // ---- epilogue.  C elem: m = m0+wr*64+i*16+hi*4+r,  n = n0+wc*64+j*16+lo
    const int nb = n0 + wc * 64;
    const int mb = m0 + wr * 64;
    if (n0 < 2048) {          // Q: rope + 1/8 scale
#pragma unroll
        for (int j = 0; j < 4; j++) {
            const int n = nb + j * 16 + lo;
            const int h = n >> 6, d = n & 63, p = d >> 1;
            const int odd = d & 1;
#pragma unroll
            for (int i = 0; i < 4; i++)
#pragma unroll
                for (int r = 0; r < 4; r++) {
                    int mg = mb + i * 16 + hi * 4 + r;
                    int b = mg >> 11, s = mg & (SEQ - 1);
                    float v = acc[i][j][r];
                    float part = __shfl_xor(v, 1);
                    float c = cosT[s * 32 + p], sn = sinT[s * 32 + p];
                    float o = odd ? (part * sn + v * c) : (v * c - part * sn);
                    qb[(((long)b * NH + h) * SEQ + s) * 64 + d] = f2bf(o * 0.125f);
                }
        }
    } else if (n0 < 2560) {   // K: rope
#pragma unroll
        for (int j = 0; j < 4; j++) {
            const int n = nb + j * 16 + lo - 2048;
            const int h = n >> 6, d = n & 63, p = d >> 1;
            const int odd = d & 1;
#pragma unroll
            for (int i = 0; i < 4; i++)
#pragma unroll
                for (int r = 0; r < 4; r++) {
                    int mg = mb + i * 16 + hi * 4 + r;
                    int b = mg >> 11, s = mg & (SEQ - 1);
                    float v = acc[i][j][r];
                    float part = __shfl_xor(v, 1);
                    float c = cosT[s * 32 + p], sn = sinT[s * 32 + p];
                    float o = odd ? (part * sn + v * c) : (v * c - part * sn);
                    kb[(((long)b * NKV + h) * SEQ + s) * 64 + d] = f2bf(o);
                }
        }
    } else {                  // V: transposed store [b][hk][64][S]
#pragma unroll
        for (int j = 0; j < 4; j++) {
            const int n = nb + j * 16 + lo - 2560;
            const int h = n >> 6, d = n & 63;
#pragma unroll
            for (int i = 0; i < 4; i++) {
                int mg = mb + i * 16 + hi * 4;
                int b = mg >> 11, s = mg & (SEQ - 1);
                ushort4 pk;
                pk.x = f2bf(acc[i][j][0]); pk.y = f2bf(acc[i][j][1]);
                pk.z = f2bf(acc[i][j][2]); pk.w = f2bf(acc[i][j][3]);
                *(ushort4*)&vt[(((long)b * NKV + h) * 64 + d) * SEQ + s] = pk;
            }
        }
    }
}

// ---------------------------------------------------------------------------
// wo GEMM, split-bf16 (hi/lo).  (unchanged, validated round 8)
// ---------------------------------------------------------------------------
__global__ __launch_bounds__(256) void gemm_wo(const unsigned short* __restrict__ Ah_,
                                               const unsigned short* __restrict__ Al_,
                                               const unsigned short* __restrict__ Bh_,
                                               const unsigned short* __restrict__ Bl_,
                                               float* __restrict__ C) {
    constexpr int K = DIM, N = DIM;
    __shared__ unsigned short sAh[128 * 32], sAl[128 * 32];
    __shared__ unsigned short sBh[128 * 32], sBl[128 * 32];

    const int t = threadIdx.x, w = t >> 6, ln = t & 63;
    const int lo = ln & 15, hi = ln >> 4;
    const int wr = w >> 1, wc = w & 1;
    const int m0 = blockIdx.y * 128, n0 = blockIdx.x * 128;

    f32x4 acc[4][4];
#pragma unroll
    for (int i = 0; i < 4; i++)
#pragma unroll
        for (int j = 0; j < 4; j++) acc[i][j] = (f32x4){0.f, 0.f, 0.f, 0.f};

    const int srow = ln >> 2, scol = (ln & 3) * 8;
    const unsigned short* pAh = Ah_ + (long)(m0 + w * 32 + srow) * K + scol;
    const unsigned short* pAl = Al_ + (long)(m0 + w * 32 + srow) * K + scol;
    const unsigned short* pBh = Bh_ + (long)(n0 + w * 32 + srow) * K + scol;
    const unsigned short* pBl = Bl_ + (long)(n0 + w * 32 + srow) * K + scol;

    for (int k0 = 0; k0 < K; k0 += 32) {
        __syncthreads();
#pragma unroll
        for (int it = 0; it < 2; it++) {
            long go = (long)it * 16 * K + k0;
            int lofs = w * 1024 + it * 512;
            gload16(pAh + go, &sAh[lofs]);
            gload16(pAl + go, &sAl[lofs]);
            gload16(pBh + go, &sBh[lofs]);
            gload16(pBl + go, &sBl[lofs]);
        }
        __syncthreads();

        bf16x8 ah[4], al[4], bh[4], bl[4];
#pragma unroll
        for (int i = 0; i < 4; i++) {
            ah[i] = *(const bf16x8*)&sAh[(wr * 64 + i * 16 + lo) * 32 + hi * 8];
            al[i] = *(const bf16x8*)&sAl[(wr * 64 + i * 16 + lo) * 32 + hi * 8];
            bh[i] = *(const bf16x8*)&sBh[(wc * 64 + i * 16 + lo) * 32 + hi * 8];
            bl[i] = *(const bf16x8*)&sBl[(wc * 64 + i * 16 + lo) * 32 + hi * 8];
        }
#pragma unroll
        for (int i = 0; i < 4; i++)
#pragma unroll
            for (int j = 0; j < 4; j++) {
                acc[i][j] = __builtin_amdgcn_mfma_f32_16x16x32_bf16(ah[i], bh[j], acc[i][j], 0, 0, 0);
                acc[i][j] = __builtin_amdgcn_mfma_f32_16x16x32_bf16(ah[i], bl[j], acc[i][j], 0, 0, 0);
                acc[i][j] = __builtin_amdgcn_mfma_f32_16x16x32_bf16(al[i], bh[j], acc[i][j], 0, 0, 0);
            }
    }

#pragma unroll
    for (int j = 0; j < 4; j++) {
        const int n = n0 + wc * 64 + j * 16 + lo;
#pragma unroll
        for (int i = 0; i < 4; i++)
#pragma unroll
            for (int r = 0; r < 4; r++)
                C[(long)(m0 + wr * 64 + i * 16 + hi * 4 + r) * N + n] = acc[i][j][r];
    }
}

// ---------------------------------------------------------------------------
// bf16 MFMA flash attention, SWAPPED QK^T (S^T = K·Q^T): each lane owns one
// q-row (q = lo) in BOTH the QK^T output and PV accumulator layouts.
//  - row max/sum: 15 in-lane ops + 2 shfl_xor (vs 8 shfl per row-group)
//  - P store: consecutive regs = consecutive k -> direct ushort4 stores, 0 shfl
//  - alpha / l lane-local -> no Aux LDS round-trip
// Causal load balance: qb_ reversed so longest blocks dispatch first.
// ---------------------------------------------------------------------------
__global__ __launch_bounds__(256) void attn_mfma(const unsigned short* __restrict__ Q,
                                                 const unsigned short* __restrict__ K,
                                                 const unsigned short* __restrict__ VT,
                                                 unsigned short* __restrict__ Oh,
                                                 unsigned short* __restrict__ Ol) {
    __shared__ __align__(16) unsigned short Kl[64 * 72];
    __shared__ __align__(16) unsigned short Vl[64 * 72];
    __shared__ __align__(16) unsigned short Pl[4][16 * 72];

    const int t = threadIdx.x, w = t >> 6, ln = t & 63;
    const int lo = ln & 15, hi = ln >> 4;
    const int qb_ = (gridDim.x - 1) - blockIdx.x;   // longest blocks launch first
    const int bh = blockIdx.y;
    const int b = bh >> 5, h = bh & 31, hk = h >> 2;
    const int q0 = qb_ * 64;

    const unsigned short* qp = Q + (((long)b * NH + h) * SEQ + q0 + w * 16) * 64;
    const unsigned short* kp = K + ((long)b * NKV + hk) * (long)SEQ * 64;
    const unsigned short* vp = VT + ((long)b * NKV + hk) * (long)HD * SEQ;

    // Q fragment (B operand of swapped QK^T): lane holds q=lo, d=hi*8+j
    bf16x8 qf0 = *(const bf16x8*)(qp + lo * 64 + hi * 8);
    bf16x8 qf1 = *(const bf16x8*)(qp + lo * 64 + 32 + hi * 8);

    f32x4 acc[4];            // O^T: lane holds q=lo, d = dt*16 + hi*4 + reg
    float m = -1e30f, l = 0.f;
#pragma unroll
    for (int i = 0; i < 4; i++) acc[i] = (f32x4){0.f, 0.f, 0.f, 0.f};

    const int rL  = ln >> 3;
    const int cc8 = (ln & 7) * 8;
    const int row0 = w * 8 + rL;
    const int qg = q0 + w * 16 + lo;       // this lane's q-row
    const int qmin = q0 + w * 16;          // wave's smallest q

    const int nt = qb_ + 1;
    for (int kt = 0; kt < nt; kt++) {
        const int k0 = kt * 64;
        // issue global loads early (hide under barrier wait)
        bf16x8 kr0 = *(const bf16x8*)(kp + (long)(k0 + row0) * 64 + cc8);
        bf16x8 kr1 = *(const bf16x8*)(kp + (long)(k0 + 32 + row0) * 64 + cc8);
        bf16x8 vr0 = *(const bf16x8*)(vp + (long)row0 * SEQ + k0 + cc8);
        bf16x8 vr1 = *(const bf16x8*)(vp + (long)(32 + row0) * SEQ + k0 + cc8);
        __syncthreads();   // prev iteration's LDS reads complete
        *(bf16x8*)&Kl[row0 * 72 + cc8]        = kr0;
        *(bf16x8*)&Kl[(row0 + 32) * 72 + cc8] = kr1;
        *(bf16x8*)&Vl[row0 * 72 + cc8]        = vr0;
        *(bf16x8*)&Vl[(row0 + 32) * 72 + cc8] = vr1;
        __syncthreads();   // staging visible

        // ---- swapped QK^T: sc[k16] = S^T tile, lane holds q=lo,
        //      k = k0 + k16*16 + hi*4 + reg
        f32x4 sc[4];
#pragma unroll
        for (int k16 = 0; k16 < 4; k16++) {
            bf16x8 kf0 = *(const bf16x8*)&Kl[(k16 * 16 + lo) * 72 + hi * 8];
            bf16x8 kf1 = *(const bf16x8*)&Kl[(k16 * 16 + lo) * 72 + 32 + hi * 8];
            f32x4 z = {0.f, 0.f, 0.f, 0.f};
            z = __builtin_amdgcn_mfma_f32_16x16x32_bf16(kf0, qf0, z, 0, 0, 0);
            sc[k16] = __builtin_amdgcn_mfma_f32_16x16x32_bf16(kf1, qf1, z, 0, 0, 0);
        }

        // ---- online softmax, row fully lane-local except 2 shfl per reduce
        float pv[4][4];
        float pmax = -1e30f;
        if (k0 + 63 > qmin) {   // wave-uniform: some k may exceed some q
#pragma unroll
            for (int k16 = 0; k16 < 4; k16++)
#pragma unroll
                for (int r = 0; r < 4; r++) {
                    float v = sc[k16][r];
                    v = (k0 + k16 * 16 + hi * 4 + r <= qg) ? v : -1e30f;
                    pv[k16][r] = v;
                    pmax = fmaxf(pmax, v);
                }
        } else {                // tile fully below diagonal: no masking
#pragma unroll
            for (int k16 = 0; k16 < 4; k16++)
#pragma unroll
                for (int r = 0; r < 4; r++) {
                    pv[k16][r] = sc[k16][r];
                    pmax = fmaxf(pmax, sc[k16][r]);
                }
        }
        // lanes sharing lo differ only in hi (bits 4..5): reduce across them
        pmax = fmaxf(pmax, __shfl_xor(pmax, 16));
        pmax = fmaxf(pmax, __shfl_xor(pmax, 32));
        float mn = fmaxf(m, pmax);
        float alpha = __expf(m - mn);
        m = mn;
        float ps = 0.f;
#pragma unroll
        for (int k16 = 0; k16 < 4; k16++)
#pragma unroll
            for (int r = 0; r < 4; r++) {
                float e = __expf(pv[k16][r] - mn);
                pv[k16][r] = e;
                ps += e;
            }
        ps += __shfl_xor(ps, 16);
        ps += __shfl_xor(ps, 32);
        l = l * alpha + ps;
#pragma unroll
        for (int dt = 0; dt < 4; dt++) {
            acc[dt][0] *= alpha; acc[dt][1] *= alpha;
            acc[dt][2] *= alpha; acc[dt][3] *= alpha;
        }

        // ---- P -> per-wave LDS: consecutive regs are consecutive k
#pragma unroll
        for (int k16 = 0; k16 < 4; k16++) {
            ushort4 pk;
            pk.x = f2bf(pv[k16][0]); pk.y = f2bf(pv[k16][1]);
            pk.z = f2bf(pv[k16][2]); pk.w = f2bf(pv[k16][3]);
            *(ushort4*)&Pl[w][lo * 72 + k16 * 16 + hi * 4] = pk;
        }
        // wave-private LDS: same-wave DS ops are ordered; no barrier needed

        // ---- PV:  O^T[d][q] += V^T[d][k] P^T[k][q]
        bf16x8 pf0 = *(const bf16x8*)&Pl[w][lo * 72 + hi * 8];        // P[q=lo][k=hi*8+j]
        bf16x8 pf1 = *(const bf16x8*)&Pl[w][lo * 72 + 32 + hi * 8];   // k+32
#pragma unroll
        for (int dt = 0; dt < 4; dt++) {
            bf16x8 vf0 = *(const bf16x8*)&Vl[(dt * 16 + lo) * 72 + hi * 8];
            bf16x8 vf1 = *(const bf16x8*)&Vl[(dt * 16 + lo) * 72 + 32 + hi * 8];
            acc[dt] = __builtin_amdgcn_mfma_f32_16x16x32_bf16(vf0, pf0, acc[dt], 0, 0, 0);
            acc[dt] = __builtin_amdgcn_mfma_f32_16x16x32_bf16(vf1, pf1, acc[dt], 0, 0, 0);
        }
    }

    // ---- epilogue: lane holds q = lo, d = dt*16 + hi*4 + reg; l lane-local
    float linv = 1.f / l;
    long rowo = (long)(b * SEQ + qg) * (NH * HD) + h * 64;
#pragma unroll
    for (int dt = 0; dt < 4; dt++) {
        float o0 = acc[dt][0] * linv, o1 = acc[dt][1] * linv;
        float o2 = acc[dt][2] * linv, o3 = acc[dt][3] * linv;
        ushort4 hv, lv;
        hv.x = f2bf(o0); hv.y = f2bf(o1); hv.z = f2bf(o2); hv.w = f2bf(o3);
        lv.x = f2bf(o0 - bf2f(hv.x)); lv.y = f2bf(o1 - bf2f(hv.y));
        lv.z = f2bf(o2 - bf2f(hv.z)); lv.w = f2bf(o3 - bf2f(hv.w));
        *(ushort4*)&Oh[rowo + dt * 16 + hi * 4] = hv;
        *(ushort4*)&Ol[rowo + dt * 16 + hi * 4] = lv;
    }
}

// ---------------------------------------------------------------------------
extern "C" void kernel_launch(void* const* d_in, const int* in_sizes, int n_in,
                              void* d_out, int out_size, void* d_ws, size_t ws_size,
                              hipStream_t stream) {
    const float* x  = (const float*)d_in[0];
    const float* wq = (const float*)d_in[1];
    const float* wk = (const float*)d_in[2];
    const float* wv = (const float*)d_in[3];
    const float* wo = (const float*)d_in[4];
    float* out = (float*)d_out;

    char* ws = (char*)d_ws;
    long off = 0;
    float* cosT = (float*)(ws + off);                 off += (long)SEQ * 32 * 4;
    float* sinT = (float*)(ws + off);                 off += (long)SEQ * 32 * 4;
    unsigned short* xb    = (unsigned short*)(ws + off); off += (long)MROWS * DIM * 2;     // 16MB
    unsigned short* wqkvT = (unsigned short*)(ws + off); off += (long)3072 * DIM * 2;      // 12MB
    unsigned short* woTh  = (unsigned short*)(ws + off); off += (long)DIM * DIM * 2;       // 8MB
    unsigned short* woTl  = (unsigned short*)(ws + off); off += (long)DIM * DIM * 2;       // 8MB
    unsigned short* qb    = (unsigned short*)(ws + off); off += (long)2 * NH * SEQ * HD * 2;   // 16MB
    unsigned short* kb    = (unsigned short*)(ws + off); off += (long)2 * NKV * SEQ * HD * 2;  // 4MB
    unsigned short* vt    = (unsigned short*)(ws + off); off += (long)2 * NKV * SEQ * HD * 2;  // 4MB
    unsigned short* aoh   = (unsigned short*)(ws + off); off += (long)MROWS * DIM * 2;     // 16MB
    unsigned short* aol   = (unsigned short*)(ws + off); off += (long)MROWS * DIM * 2;     // 16MB

    rope_table_k<<<SEQ * 32 / 256, 256, 0, stream>>>(cosT, sinT);
    cast_x_k<<<MROWS * DIM / 2048, 256, 0, stream>>>(x, xb);
    tcast_k<<<dim3(64, 64), 256, 0, stream>>>(wq, wqkvT, 2048);
    tcast_k<<<dim3(16, 64), 256, 0, stream>>>(wk, wqkvT + (long)2048 * DIM, 512);
    tcast_k<<<dim3(16, 64), 256, 0, stream>>>(wv, wqkvT + (long)2560 * DIM, 512);
    tcast_hilo_k<<<dim3(64, 64), 256, 0, stream>>>(wo, woTh, woTl);

    // fused QKV projection (bf16 MFMA) with rope/scale/V-transpose epilogue
    gemm_qkv<<<dim3(3072 / 128, MROWS / 128), 256, 0, stream>>>(
        xb, wqkvT, qb, kb, vt, cosT, sinT);

    // causal GQA flash attention (bf16 MFMA, swapped QK^T) -> hi/lo bf16 output
    attn_mfma<<<dim3(SEQ / 64, 2 * NH), 256, 0, stream>>>(qb, kb, vt, aoh, aol);

    // output projection, split-bf16 (fp32-class accuracy)
    gemm_wo<<<dim3(DIM / 128, MROWS / 128), 256, 0, stream>>>(
        aoh, aol, woTh, woTl, out);
}

// Round 11
// 459.407 us; speedup vs baseline: 6.5092x; 1.0219x over previous
//
#include <hip/hip_runtime.h>
#include <hip/hip_bf16.h>
#include <math.h>

// Problem constants (fixed by reference)
#define NH 32
#define NKV 8
#define HD 64
constexpr int SEQ  = 2048;
constexpr int DIM  = 2048;
constexpr int MROWS = 2 * SEQ;   // B*S = 4096

typedef __attribute__((ext_vector_type(8))) short bf16x8;   // 8 bf16 = 4 VGPRs (MFMA A/B frag)
typedef __attribute__((ext_vector_type(4))) float f32x4;    // MFMA C/D frag

__device__ __forceinline__ unsigned short f2bf(float f) {   // RNE float->bf16
    unsigned int u = __float_as_uint(f);
    u += 0x7fffu + ((u >> 16) & 1u);
    return (unsigned short)(u >> 16);
}
__device__ __forceinline__ float bf2f(unsigned short h) {
    return __uint_as_float((unsigned int)h << 16);
}

// async global->LDS, 16B per lane.  LDS dst must be wave-uniform (HW adds lane*16).
__device__ __forceinline__ void gload16(const void* g, void* l) {
    __builtin_amdgcn_global_load_lds(
        (const __attribute__((address_space(1))) unsigned int*)g,
        (__attribute__((address_space(3))) unsigned int*)l, 16, 0, 0);
}

// ---------------------------------------------------------------------------
// RoPE cos/sin tables: [S][32].
// ---------------------------------------------------------------------------
__global__ __launch_bounds__(256) void rope_table_k(float* __restrict__ cosT,
                                                    float* __restrict__ sinT) {
    int i = blockIdx.x * 256 + threadIdx.x;   // i < SEQ*32
    int s = i >> 5, p = i & 31;
    float inv = (float)pow(10000.0, -(double)p / 32.0);
    float a = (float)s * inv;
    cosT[i] = cosf(a);
    sinT[i] = sinf(a);
}

// ---------------------------------------------------------------------------
// cast fp32 -> bf16, 8 elems/thread
// ---------------------------------------------------------------------------
__global__ __launch_bounds__(256) void cast_x_k(const float* __restrict__ X,
                                                unsigned short* __restrict__ Xb) {
    long i = ((long)blockIdx.x * 256 + threadIdx.x) * 8;
    float4 a = *(const float4*)(X + i);
    float4 b = *(const float4*)(X + i + 4);
    ushort4 o0, o1;
    o0.x = f2bf(a.x); o0.y = f2bf(a.y); o0.z = f2bf(a.z); o0.w = f2bf(a.w);
    o1.x = f2bf(b.x); o1.y = f2bf(b.y); o1.z = f2bf(b.z); o1.w = f2bf(b.w);
    *(ushort4*)(Xb + i)     = o0;
    *(ushort4*)(Xb + i + 4) = o1;
}

// ---------------------------------------------------------------------------
// transpose+cast: W fp32 [DIM][Nw] -> T bf16 [Nw][DIM] (row stride DIM)
// ---------------------------------------------------------------------------
__global__ __launch_bounds__(256) void tcast_k(const float* __restrict__ W,
                                               unsigned short* __restrict__ T,
                                               int Nw) {
    __shared__ float Ts[32][36];
    const int t = threadIdx.x;
    const int k0 = blockIdx.y * 32, n0 = blockIdx.x * 32;
    const int r = t >> 3, c4 = (t & 7) * 4;
    *(float4*)&Ts[r][c4] = *(const float4*)(W + (long)(k0 + r) * Nw + n0 + c4);
    __syncthreads();
    ushort4 o;
    o.x = f2bf(Ts[c4 + 0][r]); o.y = f2bf(Ts[c4 + 1][r]);
    o.z = f2bf(Ts[c4 + 2][r]); o.w = f2bf(Ts[c4 + 3][r]);
    *(ushort4*)(T + (long)(n0 + r) * DIM + k0 + c4) = o;
}

// transpose + split into hi/lo bf16 (for fp32-accuracy wo GEMM)
__global__ __launch_bounds__(256) void tcast_hilo_k(const float* __restrict__ W,
                                                    unsigned short* __restrict__ Th,
                                                    unsigned short* __restrict__ Tl) {
    __shared__ float Ts[32][36];
    const int t = threadIdx.x;
    const int k0 = blockIdx.y * 32, n0 = blockIdx.x * 32;
    const int r = t >> 3, c4 = (t & 7) * 4;
    *(float4*)&Ts[r][c4] = *(const float4*)(W + (long)(k0 + r) * DIM + n0 + c4);
    __syncthreads();
    ushort4 oh, ol;
    float v0 = Ts[c4 + 0][r], v1 = Ts[c4 + 1][r], v2 = Ts[c4 + 2][r], v3 = Ts[c4 + 3][r];
    oh.x = f2bf(v0); oh.y = f2bf(v1); oh.z = f2bf(v2); oh.w = f2bf(v3);
    ol.x = f2bf(v0 - bf2f(oh.x)); ol.y = f2bf(v1 - bf2f(oh.y));
    ol.z = f2bf(v2 - bf2f(oh.z)); ol.w = f2bf(v3 - bf2f(oh.w));
    long o = (long)(n0 + r) * DIM + k0 + c4;
    *(ushort4*)(Th + o) = oh;
    *(ushort4*)(Tl + o) = ol;
}

// ---------------------------------------------------------------------------
// Fused QKV bf16 MFMA GEMM.  Q pre-scale now folds log2(e) so attention's
// softmax runs in exp2 domain (saves a v_mul per exp).
// ---------------------------------------------------------------------------
__global__ __launch_bounds__(256) void gemm_qkv(const unsigned short* __restrict__ A,
                                                const unsigned short* __restrict__ Bt,
                                                unsigned short* __restrict__ qb,
                                                unsigned short* __restrict__ kb,
                                                unsigned short* __restrict__ vt,
                                                const float* __restrict__ cosT,
                                                const float* __restrict__ sinT) {
    constexpr int K = DIM;
    __shared__ unsigned short Als[128 * 64];
    __shared__ unsigned short Bls[128 * 64];

    const int t = threadIdx.x, w = t >> 6, ln = t & 63;
    const int lo = ln & 15, hi = ln >> 4;
    const int wr = w >> 1, wc = w & 1;
    const int m0 = blockIdx.y * 128, n0 = blockIdx.x * 128;

    f32x4 acc[4][4];
#pragma unroll
    for (int i = 0; i < 4; i++)
#pragma unroll
        for (int j = 0; j < 4; j++) acc[i][j] = (f32x4){0.f, 0.f, 0.f, 0.f};

    const int srow = ln >> 3, scol = (ln & 7) * 8;
    const unsigned short* Ab = A  + (long)(m0 + w * 32 + srow) * K + scol;
    const unsigned short* Bb = Bt + (long)(n0 + w * 32 + srow) * K + scol;
    unsigned short* Alw = &Als[w * 2048];
    unsigned short* Blw = &Bls[w * 2048];

    for (int k0 = 0; k0 < K; k0 += 64) {
        __syncthreads();
#pragma unroll
        for (int it = 0; it < 4; it++) {
            gload16(Ab + (long)it * 8 * K + k0, Alw + it * 512);
            gload16(Bb + (long)it * 8 * K + k0, Blw + it * 512);
        }
        __syncthreads();

        bf16x8 af[4][2], bfr[4][2];
#pragma unroll
        for (int i = 0; i < 4; i++) {
            af[i][0]  = *(const bf16x8*)&Als[(wr * 64 + i * 16 + lo) * 64 + hi * 8];
            af[i][1]  = *(const bf16x8*)&Als[(wr * 64 + i * 16 + lo) * 64 + 32 + hi * 8];
            bfr[i][0] = *(const bf16x8*)&Bls[(wc * 64 + i * 16 + lo) * 64 + hi * 8];
            bfr[i][1] = *(const bf16x8*)&Bls[(wc * 64 + i * 16 + lo) * 64 + 32 + hi * 8];
        }
#pragma unroll
        for (int i = 0; i < 4; i++)
#pragma unroll
            for (int j = 0; j < 4; j++) {
                acc[i][j] = __builtin_amdgcn_mfma_f32_16x16x32_bf16(af[i][0], bfr[j][0], acc[i][j], 0, 0, 0);
                acc[i][j] = __builtin_amdgcn_mfma_f32_16x16x32_bf16(af[i][1], bfr[j][1], acc[i][j], 0, 0, 0);
            }
    }

    // ---- epilogue.  C elem: m = m0+wr*64+i*16+hi*4+r,  n = n0+wc*64+j*16+lo
    const int nb = n0 + wc * 64;
    const int mb = m0 + wr * 64;
    if (n0 < 2048) {          // Q: rope + (1/8)*log2(e) scale (exp2-domain softmax)
        constexpr float qsc = 0.125f * 1.44269504088896340736f;
#pragma unroll
        for (int j = 0; j < 4; j++) {
            const int n = nb + j * 16 + lo;
            const int h = n >> 6, d = n & 63, p = d >> 1;
            const int odd = d & 1;
#pragma unroll
            for (int i = 0; i < 4; i++)
#pragma unroll
                for (int r = 0; r < 4; r++) {
                    int mg = mb + i * 16 + hi * 4 + r;
                    int b = mg >> 11, s = mg & (SEQ - 1);
                    float v = acc[i][j][r];
                    float part = __shfl_xor(v, 1);
                    float c = cosT[s * 32 + p], sn = sinT[s * 32 + p];
                    float o = odd ? (part * sn + v * c) : (v * c - part * sn);
                    qb[(((long)b * NH + h) * SEQ + s) * 64 + d] = f2bf(o * qsc);
                }
        }
    } else if (n0 < 2560) {   // K: rope
#pragma unroll
        for (int j = 0; j < 4; j++) {
            const int n = nb + j * 16 + lo - 2048;
            const int h = n >> 6, d = n & 63, p = d >> 1;
            const int odd = d & 1;
#pragma unroll
            for (int i = 0; i < 4; i++)
#pragma unroll
                for (int r = 0; r < 4; r++) {
                    int mg = mb + i * 16 + hi * 4 + r;
                    int b = mg >> 11, s = mg & (SEQ - 1);
                    float v = acc[i][j][r];
                    float part = __shfl_xor(v, 1);
                    float c = cosT[s * 32 + p], sn = sinT[s * 32 + p];
                    float o = odd ? (part * sn + v * c) : (v * c - part * sn);
                    kb[(((long)b * NKV + h) * SEQ + s) * 64 + d] = f2bf(o);
                }
        }
    } else {                  // V: transposed store [b][hk][64][S]
#pragma unroll
        for (int j = 0; j < 4; j++) {
            const int n = nb + j * 16 + lo - 2560;
            const int h = n >> 6, d = n & 63;
#pragma unroll
            for (int i = 0; i < 4; i++) {
                int mg = mb + i * 16 + hi * 4;
                int b = mg >> 11, s = mg & (SEQ - 1);
                ushort4 pk;
                pk.x = f2bf(acc[i][j][0]); pk.y = f2bf(acc[i][j][1]);
                pk.z = f2bf(acc[i][j][2]); pk.w = f2bf(acc[i][j][3]);
                *(ushort4*)&vt[(((long)b * NKV + h) * 64 + d) * SEQ + s] = pk;
            }
        }
    }
}

// ---------------------------------------------------------------------------
// wo GEMM, split-bf16 (hi/lo).  (unchanged, validated round 8)
// ---------------------------------------------------------------------------
__global__ __launch_bounds__(256) void gemm_wo(const unsigned short* __restrict__ Ah_,
                                               const unsigned short* __restrict__ Al_,
                                               const unsigned short* __restrict__ Bh_,
                                               const unsigned short* __restrict__ Bl_,
                                               float* __restrict__ C) {
    constexpr int K = DIM, N = DIM;
    __shared__ unsigned short sAh[128 * 32], sAl[128 * 32];
    __shared__ unsigned short sBh[128 * 32], sBl[128 * 32];

    const int t = threadIdx.x, w = t >> 6, ln = t & 63;
    const int lo = ln & 15, hi = ln >> 4;
    const int wr = w >> 1, wc = w & 1;
    const int m0 = blockIdx.y * 128, n0 = blockIdx.x * 128;

    f32x4 acc[4][4];
#pragma unroll
    for (int i = 0; i < 4; i++)
#pragma unroll
        for (int j = 0; j < 4; j++) acc[i][j] = (f32x4){0.f, 0.f, 0.f, 0.f};

    const int srow = ln >> 2, scol = (ln & 3) * 8;
    const unsigned short* pAh = Ah_ + (long)(m0 + w * 32 + srow) * K + scol;
    const unsigned short* pAl = Al_ + (long)(m0 + w * 32 + srow) * K + scol;
    const unsigned short* pBh = Bh_ + (long)(n0 + w * 32 + srow) * K + scol;
    const unsigned short* pBl = Bl_ + (long)(n0 + w * 32 + srow) * K + scol;

    for (int k0 = 0; k0 < K; k0 += 32) {
        __syncthreads();
#pragma unroll
        for (int it = 0; it < 2; it++) {
            long go = (long)it * 16 * K + k0;
            int lofs = w * 1024 + it * 512;
            gload16(pAh + go, &sAh[lofs]);
            gload16(pAl + go, &sAl[lofs]);
            gload16(pBh + go, &sBh[lofs]);
            gload16(pBl + go, &sBl[lofs]);
        }
        __syncthreads();

        bf16x8 ah[4], al[4], bh[4], bl[4];
#pragma unroll
        for (int i = 0; i < 4; i++) {
            ah[i] = *(const bf16x8*)&sAh[(wr * 64 + i * 16 + lo) * 32 + hi * 8];
            al[i] = *(const bf16x8*)&sAl[(wr * 64 + i * 16 + lo) * 32 + hi * 8];
            bh[i] = *(const bf16x8*)&sBh[(wc * 64 + i * 16 + lo) * 32 + hi * 8];
            bl[i] = *(const bf16x8*)&sBl[(wc * 64 + i * 16 + lo) * 32 + hi * 8];
        }
#pragma unroll
        for (int i = 0; i < 4; i++)
#pragma unroll
            for (int j = 0; j < 4; j++) {
                acc[i][j] = __builtin_amdgcn_mfma_f32_16x16x32_bf16(ah[i], bh[j], acc[i][j], 0, 0, 0);
                acc[i][j] = __builtin_amdgcn_mfma_f32_16x16x32_bf16(ah[i], bl[j], acc[i][j], 0, 0, 0);
                acc[i][j] = __builtin_amdgcn_mfma_f32_16x16x32_bf16(al[i], bh[j], acc[i][j], 0, 0, 0);
            }
    }

#pragma unroll
    for (int j = 0; j < 4; j++) {
        const int n = n0 + wc * 64 + j * 16 + lo;
#pragma unroll
        for (int i = 0; i < 4; i++)
#pragma unroll
            for (int r = 0; r < 4; r++)
                C[(long)(m0 + wr * 64 + i * 16 + hi * 4 + r) * N + n] = acc[i][j][r];
    }
}

// ---------------------------------------------------------------------------
// bf16 MFMA flash attention, swapped QK^T (validated round 9) + this round:
//  - reg-prefetch pipeline: tile kt+1's K/V global loads issue right after
//    tile kt's LDS write, so QK^T+softmax+PV covers the load latency
//  - exp2-domain softmax (log2e pre-folded into Q scale): exp2f, no mul
//  - exact alpha==1 skip: when no lane sees a new max, skip the O-rescale
// ---------------------------------------------------------------------------
__global__ __launch_bounds__(256) void attn_mfma(const unsigned short* __restrict__ Q,
                                                 const unsigned short* __restrict__ K,
                                                 const unsigned short* __restrict__ VT,
                                                 unsigned short* __restrict__ Oh,
                                                 unsigned short* __restrict__ Ol) {
    __shared__ __align__(16) unsigned short Kl[64 * 72];
    __shared__ __align__(16) unsigned short Vl[64 * 72];
    __shared__ __align__(16) unsigned short Pl[4][16 * 72];

    const int t = threadIdx.x, w = t >> 6, ln = t & 63;
    const int lo = ln & 15, hi = ln >> 4;
    const int qb_ = (gridDim.x - 1) - blockIdx.x;   // longest blocks launch first
    const int bh = blockIdx.y;
    const int b = bh >> 5, h = bh & 31, hk = h >> 2;
    const int q0 = qb_ * 64;

    const unsigned short* qp = Q + (((long)b * NH + h) * SEQ + q0 + w * 16) * 64;
    const unsigned short* kp = K + ((long)b * NKV + hk) * (long)SEQ * 64;
    const unsigned short* vp = VT + ((long)b * NKV + hk) * (long)HD * SEQ;

    // Q fragment (B operand of swapped QK^T): lane holds q=lo, d=hi*8+j
    bf16x8 qf0 = *(const bf16x8*)(qp + lo * 64 + hi * 8);
    bf16x8 qf1 = *(const bf16x8*)(qp + lo * 64 + 32 + hi * 8);

    f32x4 acc[4];            // O^T: lane holds q=lo, d = dt*16 + hi*4 + reg
    float m = -1e30f, l = 0.f;
#pragma unroll
    for (int i = 0; i < 4; i++) acc[i] = (f32x4){0.f, 0.f, 0.f, 0.f};

    const int rL  = ln >> 3;
    const int cc8 = (ln & 7) * 8;
    const int row0 = w * 8 + rL;
    const int qg = q0 + w * 16 + lo;       // this lane's q-row
    const int qmin = q0 + w * 16;          // wave's smallest q

    const int nt = qb_ + 1;
    // ---- prologue: prefetch tile 0 into registers
    bf16x8 kr0 = *(const bf16x8*)(kp + (long)row0 * 64 + cc8);
    bf16x8 kr1 = *(const bf16x8*)(kp + (long)(32 + row0) * 64 + cc8);
    bf16x8 vr0 = *(const bf16x8*)(vp + (long)row0 * SEQ + cc8);
    bf16x8 vr1 = *(const bf16x8*)(vp + (long)(32 + row0) * SEQ + cc8);

    for (int kt = 0; kt < nt; kt++) {
        const int k0 = kt * 64;
        __syncthreads();   // prev iteration's LDS reads complete
        *(bf16x8*)&Kl[row0 * 72 + cc8]        = kr0;
        *(bf16x8*)&Kl[(row0 + 32) * 72 + cc8] = kr1;
        *(bf16x8*)&Vl[row0 * 72 + cc8]        = vr0;
        *(bf16x8*)&Vl[(row0 + 32) * 72 + cc8] = vr1;
        __syncthreads();   // staging visible

        // ---- issue NEXT tile's loads now; compute below hides the latency
        {
            const int k0n = (kt + 1 < nt ? kt + 1 : kt) * 64;
            kr0 = *(const bf16x8*)(kp + (long)(k0n + row0) * 64 + cc8);
            kr1 = *(const bf16x8*)(kp + (long)(k0n + 32 + row0) * 64 + cc8);
            vr0 = *(const bf16x8*)(vp + (long)row0 * SEQ + k0n + cc8);
            vr1 = *(const bf16x8*)(vp + (long)(32 + row0) * SEQ + k0n + cc8);
        }

        // ---- swapped QK^T: lane holds q=lo, k = k0 + k16*16 + hi*4 + reg
        f32x4 sc[4];
#pragma unroll
        for (int k16 = 0; k16 < 4; k16++) {
            bf16x8 kf0 = *(const bf16x8*)&Kl[(k16 * 16 + lo) * 72 + hi * 8];
            bf16x8 kf1 = *(const bf16x8*)&Kl[(k16 * 16 + lo) * 72 + 32 + hi * 8];
            f32x4 z = {0.f, 0.f, 0.f, 0.f};
            z = __builtin_amdgcn_mfma_f32_16x16x32_bf16(kf0, qf0, z, 0, 0, 0);
            sc[k16] = __builtin_amdgcn_mfma_f32_16x16x32_bf16(kf1, qf1, z, 0, 0, 0);
        }

        // ---- online softmax in exp2 domain; row lane-local, 2 shfl per reduce
        float pv[4][4];
        float pmax = -1e30f;
        if (k0 + 63 > qmin) {   // wave-uniform: masking needed
#pragma unroll
            for (int k16 = 0; k16 < 4; k16++)
#pragma unroll
                for (int r = 0; r < 4; r++) {
                    float v = sc[k16][r];
                    v = (k0 + k16 * 16 + hi * 4 + r <= qg) ? v : -1e30f;
                    pv[k16][r] = v;
                    pmax = fmaxf(pmax, v);
                }
        } else {                // tile fully below diagonal
#pragma unroll
            for (int k16 = 0; k16 < 4; k16++)
#pragma unroll
                for (int r = 0; r < 4; r++) {
                    pv[k16][r] = sc[k16][r];
                    pmax = fmaxf(pmax, sc[k16][r]);
                }
        }
        pmax = fmaxf(pmax, __shfl_xor(pmax, 16));
        pmax = fmaxf(pmax, __shfl_xor(pmax, 32));
        if (!__all(pmax <= m)) {   // new max somewhere: rescale (exact)
            float mn = fmaxf(m, pmax);
            float alpha = exp2f(m - mn);
            m = mn;
            l *= alpha;
#pragma unroll
            for (int dt = 0; dt < 4; dt++) {
                acc[dt][0] *= alpha; acc[dt][1] *= alpha;
                acc[dt][2] *= alpha; acc[dt][3] *= alpha;
            }
        }
        float ps = 0.f;
#pragma unroll
        for (int k16 = 0; k16 < 4; k16++)
#pragma unroll
            for (int r = 0; r < 4; r++) {
                float e = exp2f(pv[k16][r] - m);
                pv[k16][r] = e;
                ps += e;
            }
        ps += __shfl_xor(ps, 16);
        ps += __shfl_xor(ps, 32);
        l += ps;

        // ---- P -> per-wave LDS: consecutive regs are consecutive k
#pragma unroll
        for (int k16 = 0; k16 < 4; k16++) {
            ushort4 pk;
            pk.x = f2bf(pv[k16][0]); pk.y = f2bf(pv[k16][1]);
            pk.z = f2bf(pv[k16][2]); pk.w = f2bf(pv[k16][3]);
            *(ushort4*)&Pl[w][lo * 72 + k16 * 16 + hi * 4] = pk;
        }
        // wave-private LDS: same-wave DS ops are ordered; no barrier needed

        // ---- PV:  O^T[d][q] += V^T[d][k] P^T[k][q]
        bf16x8 pf0 = *(const bf16x8*)&Pl[w][lo * 72 + hi * 8];        // P[q=lo][k=hi*8+j]
        bf16x8 pf1 = *(const bf16x8*)&Pl[w][lo * 72 + 32 + hi * 8];   // k+32
#pragma unroll
        for (int dt = 0; dt < 4; dt++) {
            bf16x8 vf0 = *(const bf16x8*)&Vl[(dt * 16 + lo) * 72 + hi * 8];
            bf16x8 vf1 = *(const bf16x8*)&Vl[(dt * 16 + lo) * 72 + 32 + hi * 8];
            acc[dt] = __builtin_amdgcn_mfma_f32_16x16x32_bf16(vf0, pf0, acc[dt], 0, 0, 0);
            acc[dt] = __builtin_amdgcn_mfma_f32_16x16x32_bf16(vf1, pf1, acc[dt], 0, 0, 0);
        }
    }

    // ---- epilogue: lane holds q = lo, d = dt*16 + hi*4 + reg; l lane-local
    float linv = 1.f / l;
    long rowo = (long)(b * SEQ + qg) * (NH * HD) + h * 64;
#pragma unroll
    for (int dt = 0; dt < 4; dt++) {
        float o0 = acc[dt][0] * linv, o1 = acc[dt][1] * linv;
        float o2 = acc[dt][2] * linv, o3 = acc[dt][3] * linv;
        ushort4 hv, lv;
        hv.x = f2bf(o0); hv.y = f2bf(o1); hv.z = f2bf(o2); hv.w = f2bf(o3);
        lv.x = f2bf(o0 - bf2f(hv.x)); lv.y = f2bf(o1 - bf2f(hv.y));
        lv.z = f2bf(o2 - bf2f(hv.z)); lv.w = f2bf(o3 - bf2f(hv.w));
        *(ushort4*)&Oh[rowo + dt * 16 + hi * 4] = hv;
        *(ushort4*)&Ol[rowo + dt * 16 + hi * 4] = lv;
    }
}

// ---------------------------------------------------------------------------
extern "C" void kernel_launch(void* const* d_in, const int* in_sizes, int n_in,
                              void* d_out, int out_size, void* d_ws, size_t ws_size,
                              hipStream_t stream) {
    const float* x  = (const float*)d_in[0];
    const float* wq = (const float*)d_in[1];
    const float* wk = (const float*)d_in[2];
    const float* wv = (const float*)d_in[3];
    const float* wo = (const float*)d_in[4];
    float* out = (float*)d_out;

    char* ws = (char*)d_ws;
    long off = 0;
    float* cosT = (float*)(ws + off);                 off += (long)SEQ * 32 * 4;
    float* sinT = (float*)(ws + off);                 off += (long)SEQ * 32 * 4;
    unsigned short* xb    = (unsigned short*)(ws + off); off += (long)MROWS * DIM * 2;     // 16MB
    unsigned short* wqkvT = (unsigned short*)(ws + off); off += (long)3072 * DIM * 2;      // 12MB
    unsigned short* woTh  = (unsigned short*)(ws + off); off += (long)DIM * DIM * 2;       // 8MB
    unsigned short* woTl  = (unsigned short*)(ws + off); off += (long)DIM * DIM * 2;       // 8MB
    unsigned short* qb    = (unsigned short*)(ws + off); off += (long)2 * NH * SEQ * HD * 2;   // 16MB
    unsigned short* kb    = (unsigned short*)(ws + off); off += (long)2 * NKV * SEQ * HD * 2;  // 4MB
    unsigned short* vt    = (unsigned short*)(ws + off); off += (long)2 * NKV * SEQ * HD * 2;  // 4MB
    unsigned short* aoh   = (unsigned short*)(ws + off); off += (long)MROWS * DIM * 2;     // 16MB
    unsigned short* aol   = (unsigned short*)(ws + off); off += (long)MROWS * DIM * 2;     // 16MB

    rope_table_k<<<SEQ * 32 / 256, 256, 0, stream>>>(cosT, sinT);
    cast_x_k<<<MROWS * DIM / 2048, 256, 0, stream>>>(x, xb);
    tcast_k<<<dim3(64, 64), 256, 0, stream>>>(wq, wqkvT, 2048);
    tcast_k<<<dim3(16, 64), 256, 0, stream>>>(wk, wqkvT + (long)2048 * DIM, 512);
    tcast_k<<<dim3(16, 64), 256, 0, stream>>>(wv, wqkvT + (long)2560 * DIM, 512);
    tcast_hilo_k<<<dim3(64, 64), 256, 0, stream>>>(wo, woTh, woTl);

    // fused QKV projection (bf16 MFMA) with rope/scale/V-transpose epilogue
    gemm_qkv<<<dim3(3072 / 128, MROWS / 128), 256, 0, stream>>>(
        xb, wqkvT, qb, kb, vt, cosT, sinT);

    // causal GQA flash attention (bf16 MFMA, swapped QK^T, reg-prefetch)
    attn_mfma<<<dim3(SEQ / 64, 2 * NH), 256, 0, stream>>>(qb, kb, vt, aoh, aol);

    // output projection, split-bf16 (fp32-class accuracy)
    gemm_wo<<<dim3(DIM / 128, MROWS / 128), 256, 0, stream>>>(
        aoh, aol, woTh, woTl, out);
}